// Round 1
// baseline (2150.482 us; speedup 1.0000x reference)
//
#include <hip/hip_runtime.h>
#include <math.h>

// ---------------------------------------------------------------------------
// GraphSAGE forward, fp32. Pipeline:
//   deg histogram -> scan (rowptr) -> CSR fill -> norms
//   h = h_in @ encW + encb
//   L x { agg = CSR-mean(h*n1)*n2 ; agg = relu(h@W1t + agg@W1b + b1) ;
//         h += relu(agg@W2 + b2) }
//   pooled mean -> 3-layer MLP -> d_out[10]
// ---------------------------------------------------------------------------

__global__ __launch_bounds__(256) void deg_kernel(const int* __restrict__ dst,
                                                  int* __restrict__ deg, int E) {
  int e = blockIdx.x * 256 + threadIdx.x;
  if (e < E) atomicAdd(&deg[dst[e]], 1);
}

__global__ __launch_bounds__(1024) void scan_kernel(const int* __restrict__ deg,
                                                    int* __restrict__ rowptr,
                                                    int* __restrict__ pos,
                                                    int N, int E) {
  __shared__ int wsum[16];
  __shared__ int carry_s;
  const int t = threadIdx.x;
  const int lane = t & 63;
  const int wv = t >> 6;
  if (t == 0) carry_s = 0;
  __syncthreads();
  const int nchunk = (N + 4095) / 4096;
  for (int c = 0; c < nchunk; ++c) {
    int base_i = c * 4096 + t * 4;
    int v[4];
#pragma unroll
    for (int j = 0; j < 4; ++j) {
      int i = base_i + j;
      v[j] = (i < N) ? deg[i] : 0;
    }
    int tsum = v[0] + v[1] + v[2] + v[3];
    int x = tsum;
#pragma unroll
    for (int d = 1; d < 64; d <<= 1) {
      int y = __shfl_up(x, d);
      if (lane >= d) x += y;
    }
    if (lane == 63) wsum[wv] = x;
    __syncthreads();
    if (wv == 0) {
      int y = (lane < 16) ? wsum[lane] : 0;
#pragma unroll
      for (int d = 1; d < 16; d <<= 1) {
        int z = __shfl_up(y, d);
        if (lane >= d) y += z;
      }
      if (lane < 16) wsum[lane] = y;
    }
    __syncthreads();
    int wbase = (wv > 0) ? wsum[wv - 1] : 0;
    int excl = carry_s + wbase + (x - tsum);
#pragma unroll
    for (int j = 0; j < 4; ++j) {
      int i = base_i + j;
      if (i < N) { rowptr[i] = excl; pos[i] = excl; }
      excl += v[j];
    }
    __syncthreads();
    if (t == 0) carry_s += wsum[15];
    __syncthreads();
  }
  if (t == 0) rowptr[N] = E;
}

__global__ __launch_bounds__(256) void fill_kernel(const int* __restrict__ src,
                                                   const int* __restrict__ dst,
                                                   int* __restrict__ pos,
                                                   int* __restrict__ colidx, int E) {
  int e = blockIdx.x * 256 + threadIdx.x;
  if (e < E) {
    int p = atomicAdd(&pos[dst[e]], 1);
    colidx[p] = src[e];
  }
}

__global__ __launch_bounds__(256) void norm_kernel(const int* __restrict__ deg,
                                                   float* __restrict__ n1,
                                                   float* __restrict__ n2, int N) {
  int i = blockIdx.x * 256 + threadIdx.x;
  if (i < N) {
    int di = deg[i];
    float d = (float)(di < 1 ? 1 : di);
    float r = 1.0f / sqrtf(d);
    n1[i] = r;        // deg^-0.5
    n2[i] = r / d;    // deg^-1.5  (inv_deg * norm)
  }
}

// agg[i] = ( sum_{e in row i} h[col[e]] * n1[col[e]] ) * n2[i]
__global__ __launch_bounds__(256) void agg_kernel(const float* __restrict__ h,
                                                  const int* __restrict__ rowptr,
                                                  const int* __restrict__ colidx,
                                                  const float* __restrict__ n1,
                                                  const float* __restrict__ n2,
                                                  float* __restrict__ agg, int N) {
  int wid = (blockIdx.x * 256 + threadIdx.x) >> 6;  // one wave per node
  int lane = threadIdx.x & 63;                      // lane covers cols 2l,2l+1
  if (wid >= N) return;
  int s = rowptr[wid], e = rowptr[wid + 1];
  const float2* h2 = (const float2*)h;
  float ax = 0.f, ay = 0.f;
  for (int i = s; i < e; ++i) {
    int c = colidx[i];
    float sc = n1[c];
    float2 v = h2[(size_t)c * 64 + lane];
    ax = fmaf(v.x, sc, ax);
    ay = fmaf(v.y, sc, ay);
  }
  float m = n2[wid];
  ((float2*)agg)[(size_t)wid * 64 + lane] = make_float2(ax * m, ay * m);
}

// out[M,128] = epilogue( A@W (+ A2@W2) + bias )
// MODE 0: out = acc + bias
// MODE 1: out = relu(acc + bias)
// MODE 2: out += relu(acc + bias)
// Tile 128 rows x 128 cols, 256 threads, 8x8 micro-tile (rows rg*4..+3 and
// rg*4+64..+67; cols cg*4..+3 and cg*4+64..+67). A staged transposed with
// XOR swizzle for conflict-free b128 fragment reads.
template <int MODE, bool TWO>
__global__ __launch_bounds__(256) void gemm128(const float* __restrict__ A,
                                               const float* __restrict__ Wg,
                                               const float* __restrict__ A2,
                                               const float* __restrict__ W2g,
                                               const float* __restrict__ bias,
                                               float* __restrict__ out, int M) {
  __shared__ float As[128 * 128];  // As[k][swz(r)] 64KB
  __shared__ float Ws[128 * 128];  // Ws[k][c]      64KB
  const int tid = threadIdx.x;
  const int brow = blockIdx.x * 128;
  const int cg = tid & 15;
  const int rg = tid >> 4;

  float acc[8][8];
#pragma unroll
  for (int i = 0; i < 8; ++i)
#pragma unroll
    for (int j = 0; j < 8; ++j) acc[i][j] = 0.f;

  const float4* A4 = (const float4*)A;
  const float4* W4 = (const float4*)Wg;

  const int nphase = TWO ? 2 : 1;
  for (int phase = 0; phase < nphase; ++phase) {
    if (phase == 1) {
      __syncthreads();
      A4 = (const float4*)A2;
      W4 = (const float4*)W2g;
    }
    // stage W (direct copy, row-major [k][c])
#pragma unroll
    for (int it = 0; it < 16; ++it)
      ((float4*)Ws)[it * 256 + tid] = W4[it * 256 + tid];
    // stage A transposed + swizzled
#pragma unroll
    for (int it = 0; it < 16; ++it) {
      int r = it * 8 + (tid >> 5);
      int grow = brow + r;
      float4 v = make_float4(0.f, 0.f, 0.f, 0.f);
      if (grow < M) v = A4[(size_t)grow * 32 + (tid & 31)];
      int k0 = (tid & 31) * 4;
#pragma unroll
      for (int j = 0; j < 4; ++j) {
        int k = k0 + j;
        As[k * 128 + (((r >> 2) ^ (k & 31)) << 2) + (r & 3)] = (&v.x)[j];
      }
    }
    __syncthreads();
#pragma unroll 4
    for (int k = 0; k < 128; ++k) {
      const int kk = k & 31;
      float4 a0 = ((const float4*)As)[k * 32 + (rg ^ kk)];
      float4 a1 = ((const float4*)As)[k * 32 + ((16 + rg) ^ kk)];
      float4 w0 = ((const float4*)Ws)[k * 32 + cg];
      float4 w1 = ((const float4*)Ws)[k * 32 + 16 + cg];
      float a[8] = {a0.x, a0.y, a0.z, a0.w, a1.x, a1.y, a1.z, a1.w};
      float w[8] = {w0.x, w0.y, w0.z, w0.w, w1.x, w1.y, w1.z, w1.w};
#pragma unroll
      for (int i = 0; i < 8; ++i)
#pragma unroll
        for (int j = 0; j < 8; ++j) acc[i][j] = fmaf(a[i], w[j], acc[i][j]);
    }
  }

  float4 b0 = make_float4(0.f, 0.f, 0.f, 0.f);
  float4 b1 = make_float4(0.f, 0.f, 0.f, 0.f);
  if (bias) {
    b0 = ((const float4*)bias)[cg];
    b1 = ((const float4*)bias)[16 + cg];
  }
#pragma unroll
  for (int i = 0; i < 8; ++i) {
    int r = (i < 4) ? (rg * 4 + i) : (rg * 4 + 64 + (i - 4));
    int grow = brow + r;
    if (grow >= M) continue;
    float o[8];
    o[0] = acc[i][0] + b0.x; o[1] = acc[i][1] + b0.y;
    o[2] = acc[i][2] + b0.z; o[3] = acc[i][3] + b0.w;
    o[4] = acc[i][4] + b1.x; o[5] = acc[i][5] + b1.y;
    o[6] = acc[i][6] + b1.z; o[7] = acc[i][7] + b1.w;
    if (MODE >= 1) {
#pragma unroll
      for (int j = 0; j < 8; ++j) o[j] = fmaxf(o[j], 0.f);
    }
    float4* op = (float4*)out + (size_t)grow * 32;
    if (MODE == 2) {
      float4 c0 = op[cg];
      float4 c1 = op[16 + cg];
      op[cg] = make_float4(c0.x + o[0], c0.y + o[1], c0.z + o[2], c0.w + o[3]);
      op[16 + cg] = make_float4(c1.x + o[4], c1.y + o[5], c1.z + o[6], c1.w + o[7]);
    } else {
      op[cg] = make_float4(o[0], o[1], o[2], o[3]);
      op[16 + cg] = make_float4(o[4], o[5], o[6], o[7]);
    }
  }
}

__global__ __launch_bounds__(256) void pool_partial(const float* __restrict__ h,
                                                    float* __restrict__ partial,
                                                    int N) {
  int col = threadIdx.x & 127;
  int stream = blockIdx.x * 2 + (threadIdx.x >> 7);
  float s = 0.f;
  for (int r = stream; r < N; r += 512) s += h[(size_t)r * 128 + col];
  partial[stream * 128 + col] = s;
}

__global__ __launch_bounds__(256) void readout_kernel(
    const float* __restrict__ partial, const float* __restrict__ rW1,
    const float* __restrict__ rb1, const float* __restrict__ rW2,
    const float* __restrict__ rb2, const float* __restrict__ rW3,
    const float* __restrict__ rb3, float* __restrict__ outp, int N) {
  __shared__ float pooled[128];
  __shared__ float x1[64];
  __shared__ float x2[32];
  int t = threadIdx.x;
  if (t < 128) {
    float s = 0.f;
    for (int i = 0; i < 512; ++i) s += partial[i * 128 + t];
    pooled[t] = s / (float)N;
  }
  __syncthreads();
  if (t < 64) {
    float s = rb1[t];
    for (int k = 0; k < 128; ++k) s = fmaf(pooled[k], rW1[k * 64 + t], s);
    x1[t] = fmaxf(s, 0.f);
  }
  __syncthreads();
  if (t < 32) {
    float s = rb2[t];
    for (int k = 0; k < 64; ++k) s = fmaf(x1[k], rW2[k * 32 + t], s);
    x2[t] = fmaxf(s, 0.f);
  }
  __syncthreads();
  if (t < 10) {
    float s = rb3[t];
    for (int k = 0; k < 32; ++k) s = fmaf(x2[k], rW3[k * 10 + t], s);
    outp[t] = s;
  }
}

extern "C" void kernel_launch(void* const* d_in, const int* in_sizes, int n_in,
                              void* d_out, int out_size, void* d_ws, size_t ws_size,
                              hipStream_t stream) {
  const float* h_in  = (const float*)d_in[0];
  const int*   src   = (const int*)d_in[1];
  const int*   dst   = (const int*)d_in[2];
  const float* enc_W = (const float*)d_in[3];
  const float* enc_b = (const float*)d_in[4];
  const float* W1    = (const float*)d_in[5];
  const float* b1    = (const float*)d_in[6];
  const float* W2    = (const float*)d_in[7];
  const float* b2    = (const float*)d_in[8];
  const float* rW1   = (const float*)d_in[9];
  const float* rb1   = (const float*)d_in[10];
  const float* rW2   = (const float*)d_in[11];
  const float* rb2   = (const float*)d_in[12];
  const float* rW3   = (const float*)d_in[13];
  const float* rb3   = (const float*)d_in[14];

  const int N = in_sizes[0] / 128;
  const int E = in_sizes[1];
  const int L = in_sizes[6] / 128;

  char* ws = (char*)d_ws;
  size_t off = 0;
  auto alloc = [&](size_t bytes) {
    char* p = ws + off;
    off = (off + bytes + 511) & ~(size_t)511;
    return p;
  };
  float* h      = (float*)alloc((size_t)N * 128 * 4);
  float* agg    = (float*)alloc((size_t)N * 128 * 4);
  int* deg      = (int*)alloc((size_t)N * 4);
  int* rowptr   = (int*)alloc((size_t)(N + 1) * 4);
  int* pos      = (int*)alloc((size_t)N * 4);
  int* colidx   = (int*)alloc((size_t)E * 4);
  float* n1     = (float*)alloc((size_t)N * 4);
  float* n2     = (float*)alloc((size_t)N * 4);
  float* partial= (float*)alloc((size_t)512 * 128 * 4);
  (void)ws_size; (void)n_in; (void)out_size;

  hipMemsetAsync(deg, 0, (size_t)N * 4, stream);
  deg_kernel<<<(E + 255) / 256, 256, 0, stream>>>(dst, deg, E);
  scan_kernel<<<1, 1024, 0, stream>>>(deg, rowptr, pos, N, E);
  fill_kernel<<<(E + 255) / 256, 256, 0, stream>>>(src, dst, pos, colidx, E);
  norm_kernel<<<(N + 255) / 256, 256, 0, stream>>>(deg, n1, n2, N);

  const int gblocks = (N + 127) / 128;
  gemm128<0, false><<<gblocks, 256, 0, stream>>>(h_in, enc_W, nullptr, nullptr,
                                                 enc_b, h, N);
  for (int l = 0; l < L; ++l) {
    agg_kernel<<<(N + 3) / 4, 256, 0, stream>>>(h, rowptr, colidx, n1, n2, agg, N);
    const float* W1t = W1 + (size_t)l * 256 * 128;
    const float* W1b = W1t + 128 * 128;
    gemm128<1, true><<<gblocks, 256, 0, stream>>>(h, W1t, agg, W1b, b1 + l * 128,
                                                  agg, N);
    gemm128<2, false><<<gblocks, 256, 0, stream>>>(agg, W2 + (size_t)l * 128 * 128,
                                                   nullptr, nullptr, b2 + l * 128,
                                                   h, N);
  }
  pool_partial<<<256, 256, 0, stream>>>(h, partial, N);
  readout_kernel<<<1, 256, 0, stream>>>(partial, rW1, rb1, rW2, rb2, rW3, rb3,
                                        (float*)d_out, N);
}

// Round 6
// 1449.107 us; speedup vs baseline: 1.4840x; 1.4840x over previous
//
#include <hip/hip_runtime.h>
#include <math.h>

typedef short short8 __attribute__((ext_vector_type(8)));
typedef float f32x4 __attribute__((ext_vector_type(4)));

#define DEV static __device__ __forceinline__

// ---- fp32 -> (hi, lo) bf16 split: x ~= hi + lo, |err| ~ 4e-6 |x| -----------
DEV unsigned int bf16h(float x) {
  unsigned int u = __float_as_uint(x);
  return (u + 0x7FFFu + ((u >> 16) & 1u)) >> 16;
}
DEV void split2(float x, unsigned int& h, unsigned int& l) {
  h = bf16h(x);
  float hf = __uint_as_float(h << 16);
  l = bf16h(x - hf);
}

// ---------------------------------------------------------------------------
// CSR build + norms
// ---------------------------------------------------------------------------
__global__ __launch_bounds__(256) void deg_kernel(const int* __restrict__ dst,
                                                  int* __restrict__ deg, int E) {
  int e = blockIdx.x * 256 + threadIdx.x;
  if (e < E) atomicAdd(&deg[dst[e]], 1);
}

__global__ __launch_bounds__(1024) void scan_kernel(const int* __restrict__ deg,
                                                    int* __restrict__ rowptr,
                                                    int* __restrict__ pos,
                                                    int N, int E) {
  __shared__ int wsum[16];
  __shared__ int carry_s;
  const int t = threadIdx.x;
  const int lane = t & 63;
  const int wv = t >> 6;
  if (t == 0) carry_s = 0;
  __syncthreads();
  const int nchunk = (N + 4095) / 4096;
  for (int c = 0; c < nchunk; ++c) {
    int base_i = c * 4096 + t * 4;
    int v[4];
#pragma unroll
    for (int j = 0; j < 4; ++j) {
      int i = base_i + j;
      v[j] = (i < N) ? deg[i] : 0;
    }
    int tsum = v[0] + v[1] + v[2] + v[3];
    int x = tsum;
#pragma unroll
    for (int d = 1; d < 64; d <<= 1) {
      int y = __shfl_up(x, d);
      if (lane >= d) x += y;
    }
    if (lane == 63) wsum[wv] = x;
    __syncthreads();
    if (wv == 0) {
      int y = (lane < 16) ? wsum[lane] : 0;
#pragma unroll
      for (int d = 1; d < 16; d <<= 1) {
        int z = __shfl_up(y, d);
        if (lane >= d) y += z;
      }
      if (lane < 16) wsum[lane] = y;
    }
    __syncthreads();
    int wbase = (wv > 0) ? wsum[wv - 1] : 0;
    int excl = carry_s + wbase + (x - tsum);
#pragma unroll
    for (int j = 0; j < 4; ++j) {
      int i = base_i + j;
      if (i < N) { rowptr[i] = excl; pos[i] = excl; }
      excl += v[j];
    }
    __syncthreads();
    if (t == 0) carry_s += wsum[15];
    __syncthreads();
  }
  if (t == 0) rowptr[N] = E;
}

__global__ __launch_bounds__(256) void fill_kernel(const int* __restrict__ src,
                                                   const int* __restrict__ dst,
                                                   int* __restrict__ pos,
                                                   int* __restrict__ colidx, int E) {
  int e = blockIdx.x * 256 + threadIdx.x;
  if (e < E) {
    int p = atomicAdd(&pos[dst[e]], 1);
    colidx[p] = src[e];
  }
}

__global__ __launch_bounds__(256) void norm_kernel(const int* __restrict__ deg,
                                                   float* __restrict__ n1,
                                                   float* __restrict__ n2, int N) {
  int i = blockIdx.x * 256 + threadIdx.x;
  if (i < N) {
    int di = deg[i];
    float d = (float)(di < 1 ? 1 : di);
    float r = 1.0f / sqrtf(d);
    n1[i] = r;
    n2[i] = r / d;
  }
}

// agg[i] = ( sum_{e in row i} h[col[e]] * n1[col[e]] ) * n2[i]
__global__ __launch_bounds__(256) void agg_kernel(const float* __restrict__ h,
                                                  const int* __restrict__ rowptr,
                                                  const int* __restrict__ colidx,
                                                  const float* __restrict__ n1,
                                                  const float* __restrict__ n2,
                                                  float* __restrict__ agg, int N) {
  int wid = (blockIdx.x * 256 + threadIdx.x) >> 6;
  int lane = threadIdx.x & 63;
  if (wid >= N) return;
  int s = rowptr[wid], e = rowptr[wid + 1];
  const float2* h2 = (const float2*)h;
  float ax = 0.f, ay = 0.f;
  for (int i = s; i < e; ++i) {
    int c = colidx[i];
    float sc = n1[c];
    float2 v = h2[(size_t)c * 64 + lane];
    ax = fmaf(v.x, sc, ax);
    ay = fmaf(v.y, sc, ay);
  }
  float m = n2[wid];
  ((float2*)agg)[(size_t)wid * 64 + lane] = make_float2(ax * m, ay * m);
}

// ---------------------------------------------------------------------------
// Weight prep: W[K][C] fp32 -> Wt_hi/lo[C][K] bf16 (transposed + split)
// ---------------------------------------------------------------------------
__global__ __launch_bounds__(256) void prep_w(const float* __restrict__ src,
                                              unsigned short* __restrict__ dh,
                                              unsigned short* __restrict__ dl,
                                              int K, int C) {
  int t = blockIdx.x * 256 + threadIdx.x;
  if (t >= K * C) return;
  int c = t / K, k = t - c * K;
  unsigned int h, l;
  split2(src[(size_t)k * C + c], h, l);
  dh[t] = (unsigned short)h;
  dl[t] = (unsigned short)l;
}

// ---------------------------------------------------------------------------
// Fused MFMA kernel. KIND 0: out = A@W1 + b1  (encoder, K=128)
// KIND 1: z = relu([A|A2] @ W1 + b1); out = A + relu(z @ W2 + b2)   (layer)
// Tile 128 rows x 128 cols, 512 threads = 8 waves (2 row-groups x 4 col-groups).
// Split-bf16: 3 MFMAs (hh, hl, lh) per fragment pair.
// LDS: As hi/lo [128][128] bf16 + Ws hi/lo [128 cols][128 k] bf16 = 128 KB,
// 16B chunks XOR-swizzled: chunk ^= (row & 7) (low 3 bits of chunk index).
// ---------------------------------------------------------------------------
template <int KIND>
__global__ __launch_bounds__(512, 2) void sage_mm(
    const float* __restrict__ A, const float* __restrict__ A2,
    const unsigned short* __restrict__ W1h, const unsigned short* __restrict__ W1l,
    const unsigned short* __restrict__ W2h, const unsigned short* __restrict__ W2l,
    const float* __restrict__ b1, const float* __restrict__ b2,
    float* __restrict__ out, int M) {
  __shared__ unsigned short AsH[128 * 128];
  __shared__ unsigned short AsL[128 * 128];
  __shared__ unsigned short WsH[128 * 128];
  __shared__ unsigned short WsL[128 * 128];

  const int t = threadIdx.x;
  const int lane = t & 63;
  const int w = t >> 6;
  const int rl = lane & 15, g = lane >> 4;
  const int rbase = (w >> 2) * 64;   // wave rows within tile
  const int cbase = (w & 3) * 32;    // wave cols within tile
  const int rowbase = blockIdx.x * 128;

  // stage full [128 cols][128 k] bf16 pair: 2048 16B-chunks, 4 per thread
  auto stageW = [&](const unsigned short* sh, const unsigned short* sl, int ldk,
                    int k0) {
#pragma unroll
    for (int j = 0; j < 4; ++j) {
      int ch = t * 4 + j;            // 0..2047
      int c = ch >> 4, cc = ch & 15; // col, 16B-chunk within col
      int off = c * 256 + ((cc ^ (c & 7)) << 4);
      *(int4*)((char*)WsH + off) = *(const int4*)(sh + (size_t)c * ldk + k0 + cc * 8);
      *(int4*)((char*)WsL + off) = *(const int4*)(sl + (size_t)c * ldk + k0 + cc * 8);
    }
  };

  auto stageA = [&](const float* __restrict__ src) {
    int r = t >> 2, kc = (t & 3) * 32;
    int grow = rowbase + r;
    const float4* s = (const float4*)(src + (size_t)grow * 128 + kc);
#pragma unroll
    for (int j = 0; j < 8; ++j) {
      float4 v = make_float4(0.f, 0.f, 0.f, 0.f);
      if (grow < M) v = s[j];
      unsigned int h0, l0, h1, l1, h2, l2, h3, l3;
      split2(v.x, h0, l0); split2(v.y, h1, l1);
      split2(v.z, h2, l2); split2(v.w, h3, l3);
      int off = r * 256 + ((2 * (kc + j * 4)) ^ ((r & 7) << 4));
      *(int2*)((char*)AsH + off) =
          make_int2((int)(h0 | (h1 << 16)), (int)(h2 | (h3 << 16)));
      *(int2*)((char*)AsL + off) =
          make_int2((int)(l0 | (l1 << 16)), (int)(l2 | (l3 << 16)));
    }
  };

  f32x4 acc[4][2];
  auto zacc = [&]() {
#pragma unroll
    for (int i = 0; i < 4; ++i)
#pragma unroll
      for (int j = 0; j < 2; ++j) {
        f32x4 z = {0.f, 0.f, 0.f, 0.f};
        acc[i][j] = z;
      }
  };

  auto kloop = [&]() {
#pragma unroll
    for (int ks = 0; ks < 4; ++ks) {
      short8 aH[4], aL[4], bH[2], bL[2];
#pragma unroll
      for (int fr = 0; fr < 4; ++fr) {
        int row = rbase + fr * 16 + rl;
        int off = row * 256 + (((ks * 4 + g) ^ (row & 7)) << 4);
        aH[fr] = *(const short8*)((const char*)AsH + off);
        aL[fr] = *(const short8*)((const char*)AsL + off);
      }
#pragma unroll
      for (int fc = 0; fc < 2; ++fc) {
        int col = cbase + fc * 16 + rl;
        int off = col * 256 + (((ks * 4 + g) ^ (col & 7)) << 4);
        bH[fc] = *(const short8*)((const char*)WsH + off);
        bL[fc] = *(const short8*)((const char*)WsL + off);
      }
#pragma unroll
      for (int fr = 0; fr < 4; ++fr)
#pragma unroll
        for (int fc = 0; fc < 2; ++fc) {
          acc[fr][fc] = __builtin_amdgcn_mfma_f32_16x16x32_bf16(
              aH[fr], bH[fc], acc[fr][fc], 0, 0, 0);
          acc[fr][fc] = __builtin_amdgcn_mfma_f32_16x16x32_bf16(
              aH[fr], bL[fc], acc[fr][fc], 0, 0, 0);
          acc[fr][fc] = __builtin_amdgcn_mfma_f32_16x16x32_bf16(
              aL[fr], bH[fc], acc[fr][fc], 0, 0, 0);
        }
    }
  };

  zacc();
  stageA(A);
  stageW(W1h, W1l, (KIND == 1) ? 256 : 128, 0);
  __syncthreads();
  kloop();

  if (KIND == 0) {
#pragma unroll
    for (int fc = 0; fc < 2; ++fc) {
      int col = cbase + fc * 16 + rl;
      float bb = b1[col];
#pragma unroll
      for (int fr = 0; fr < 4; ++fr)
#pragma unroll
        for (int q = 0; q < 4; ++q) {
          int row = rowbase + rbase + fr * 16 + g * 4 + q;
          if (row < M) out[(size_t)row * 128 + col] = acc[fr][fc][q] + bb;
        }
    }
    return;
  }

  __syncthreads();
  stageA(A2);
  stageW(W1h, W1l, 256, 128);
  __syncthreads();
  kloop();
  __syncthreads();  // everyone done reading As/Ws

  // z = relu(acc + b1) -> As (hi/lo, swizzled); stage W2
#pragma unroll
  for (int fc = 0; fc < 2; ++fc) {
    int col = cbase + fc * 16 + rl;
    float bb = b1[col];
#pragma unroll
    for (int fr = 0; fr < 4; ++fr)
#pragma unroll
      for (int q = 0; q < 4; ++q) {
        int row = rbase + fr * 16 + g * 4 + q;  // tile-relative
        float z = fmaxf(acc[fr][fc][q] + bb, 0.f);
        unsigned int h, l;
        split2(z, h, l);
        int off = row * 256 + ((2 * col) ^ ((row & 7) << 4));
        *(unsigned short*)((char*)AsH + off) = (unsigned short)h;
        *(unsigned short*)((char*)AsL + off) = (unsigned short)l;
      }
  }
  stageW(W2h, W2l, 128, 0);
  zacc();
  __syncthreads();
  kloop();

  // out = A + relu(acc + b2)
#pragma unroll
  for (int fc = 0; fc < 2; ++fc) {
    int col = cbase + fc * 16 + rl;
    float bb = b2[col];
#pragma unroll
    for (int fr = 0; fr < 4; ++fr)
#pragma unroll
      for (int q = 0; q < 4; ++q) {
        int row = rowbase + rbase + fr * 16 + g * 4 + q;
        if (row < M) {
          float z = fmaxf(acc[fr][fc][q] + bb, 0.f);
          out[(size_t)row * 128 + col] = A[(size_t)row * 128 + col] + z;
        }
      }
  }
}

// ---------------------------------------------------------------------------
// Pooling + readout
// ---------------------------------------------------------------------------
__global__ __launch_bounds__(256) void pool_partial(const float* __restrict__ h,
                                                    float* __restrict__ partial,
                                                    int N) {
  int col = threadIdx.x & 127;
  int stream = blockIdx.x * 2 + (threadIdx.x >> 7);
  float s = 0.f;
  for (int r = stream; r < N; r += 512) s += h[(size_t)r * 128 + col];
  partial[stream * 128 + col] = s;
}

__global__ __launch_bounds__(256) void readout_kernel(
    const float* __restrict__ partial, const float* __restrict__ rW1,
    const float* __restrict__ rb1, const float* __restrict__ rW2,
    const float* __restrict__ rb2, const float* __restrict__ rW3,
    const float* __restrict__ rb3, float* __restrict__ outp, int N) {
  __shared__ float pooled[128];
  __shared__ float x1[64];
  __shared__ float x2[32];
  int t = threadIdx.x;
  if (t < 128) {
    float s = 0.f;
    for (int i = 0; i < 512; ++i) s += partial[i * 128 + t];
    pooled[t] = s / (float)N;
  }
  __syncthreads();
  if (t < 64) {
    float s = rb1[t];
    for (int k = 0; k < 128; ++k) s = fmaf(pooled[k], rW1[k * 64 + t], s);
    x1[t] = fmaxf(s, 0.f);
  }
  __syncthreads();
  if (t < 32) {
    float s = rb2[t];
    for (int k = 0; k < 64; ++k) s = fmaf(x1[k], rW2[k * 32 + t], s);
    x2[t] = fmaxf(s, 0.f);
  }
  __syncthreads();
  if (t < 10) {
    float s = rb3[t];
    for (int k = 0; k < 32; ++k) s = fmaf(x2[k], rW3[k * 10 + t], s);
    outp[t] = s;
  }
}

extern "C" void kernel_launch(void* const* d_in, const int* in_sizes, int n_in,
                              void* d_out, int out_size, void* d_ws, size_t ws_size,
                              hipStream_t stream) {
  const float* h_in  = (const float*)d_in[0];
  const int*   src   = (const int*)d_in[1];
  const int*   dst   = (const int*)d_in[2];
  const float* enc_W = (const float*)d_in[3];
  const float* enc_b = (const float*)d_in[4];
  const float* W1    = (const float*)d_in[5];
  const float* b1    = (const float*)d_in[6];
  const float* W2    = (const float*)d_in[7];
  const float* b2    = (const float*)d_in[8];
  const float* rW1   = (const float*)d_in[9];
  const float* rb1   = (const float*)d_in[10];
  const float* rW2   = (const float*)d_in[11];
  const float* rb2   = (const float*)d_in[12];
  const float* rW3   = (const float*)d_in[13];
  const float* rb3   = (const float*)d_in[14];

  const int N = in_sizes[0] / 128;
  const int E = in_sizes[1];
  const int L = in_sizes[6] / 128;

  char* ws = (char*)d_ws;
  size_t off = 0;
  auto alloc = [&](size_t bytes) {
    char* p = ws + off;
    off = (off + bytes + 511) & ~(size_t)511;
    return p;
  };
  float* h       = (float*)alloc((size_t)N * 128 * 4);
  float* agg     = (float*)alloc((size_t)N * 128 * 4);
  int* deg       = (int*)alloc((size_t)N * 4);
  int* rowptr    = (int*)alloc((size_t)(N + 1) * 4);
  int* pos       = (int*)alloc((size_t)N * 4);
  int* colidx    = (int*)alloc((size_t)E * 4);
  float* n1      = (float*)alloc((size_t)N * 4);
  float* n2      = (float*)alloc((size_t)N * 4);
  float* partial = (float*)alloc((size_t)512 * 128 * 4);
  unsigned short* encWh = (unsigned short*)alloc(16384 * 2);
  unsigned short* encWl = (unsigned short*)alloc(16384 * 2);
  unsigned short* W1th  = (unsigned short*)alloc((size_t)L * 32768 * 2);
  unsigned short* W1tl  = (unsigned short*)alloc((size_t)L * 32768 * 2);
  unsigned short* W2th  = (unsigned short*)alloc((size_t)L * 16384 * 2);
  unsigned short* W2tl  = (unsigned short*)alloc((size_t)L * 16384 * 2);
  (void)ws_size; (void)n_in; (void)out_size;

  hipMemsetAsync(deg, 0, (size_t)N * 4, stream);
  deg_kernel<<<(E + 255) / 256, 256, 0, stream>>>(dst, deg, E);
  scan_kernel<<<1, 1024, 0, stream>>>(deg, rowptr, pos, N, E);
  fill_kernel<<<(E + 255) / 256, 256, 0, stream>>>(src, dst, pos, colidx, E);
  norm_kernel<<<(N + 255) / 256, 256, 0, stream>>>(deg, n1, n2, N);

  // weight prep (transpose + hi/lo split)
  prep_w<<<64, 256, 0, stream>>>(enc_W, encWh, encWl, 128, 128);
  for (int l = 0; l < L; ++l) {
    prep_w<<<128, 256, 0, stream>>>(W1 + (size_t)l * 32768,
                                    W1th + (size_t)l * 32768,
                                    W1tl + (size_t)l * 32768, 256, 128);
    prep_w<<<64, 256, 0, stream>>>(W2 + (size_t)l * 16384,
                                   W2th + (size_t)l * 16384,
                                   W2tl + (size_t)l * 16384, 128, 128);
  }

  const int gblocks = (N + 127) / 128;
  sage_mm<0><<<gblocks, 512, 0, stream>>>(h_in, nullptr, encWh, encWl, nullptr,
                                          nullptr, enc_b, nullptr, h, N);
  for (int l = 0; l < L; ++l) {
    agg_kernel<<<(N + 3) / 4, 256, 0, stream>>>(h, rowptr, colidx, n1, n2, agg, N);
    sage_mm<1><<<gblocks, 512, 0, stream>>>(
        h, agg, W1th + (size_t)l * 32768, W1tl + (size_t)l * 32768,
        W2th + (size_t)l * 16384, W2tl + (size_t)l * 16384,
        b1 + l * 128, b2 + l * 128, h, N);
  }
  pool_partial<<<256, 256, 0, stream>>>(h, partial, N);
  readout_kernel<<<1, 256, 0, stream>>>(partial, rW1, rb1, rW2, rb2, rW3, rb3,
                                        (float*)d_out, N);
}

// Round 7
// 1258.107 us; speedup vs baseline: 1.7093x; 1.1518x over previous
//
#include <hip/hip_runtime.h>
#include <math.h>

typedef short short8 __attribute__((ext_vector_type(8)));
typedef float f32x4 __attribute__((ext_vector_type(4)));

#define DEV static __device__ __forceinline__

// ---- fp32 -> (hi, lo) bf16 split: x ~= hi + lo, |err| ~ 4e-6 |x| -----------
DEV unsigned int bf16h(float x) {
  unsigned int u = __float_as_uint(x);
  return (u + 0x7FFFu + ((u >> 16) & 1u)) >> 16;
}
DEV void split2(float x, unsigned int& h, unsigned int& l) {
  h = bf16h(x);
  float hf = __uint_as_float(h << 16);
  l = bf16h(x - hf);
}

// ---------------------------------------------------------------------------
// CSR build + norms
// ---------------------------------------------------------------------------
__global__ __launch_bounds__(256) void deg_kernel(const int* __restrict__ dst,
                                                  int* __restrict__ deg, int E) {
  int e = blockIdx.x * 256 + threadIdx.x;
  if (e < E) atomicAdd(&deg[dst[e]], 1);
}

__global__ __launch_bounds__(1024) void scan_kernel(const int* __restrict__ deg,
                                                    int* __restrict__ rowptr,
                                                    int* __restrict__ pos,
                                                    int N, int E) {
  __shared__ int wsum[16];
  __shared__ int carry_s;
  const int t = threadIdx.x;
  const int lane = t & 63;
  const int wv = t >> 6;
  if (t == 0) carry_s = 0;
  __syncthreads();
  const int nchunk = (N + 4095) / 4096;
  for (int c = 0; c < nchunk; ++c) {
    int base_i = c * 4096 + t * 4;
    int v[4];
#pragma unroll
    for (int j = 0; j < 4; ++j) {
      int i = base_i + j;
      v[j] = (i < N) ? deg[i] : 0;
    }
    int tsum = v[0] + v[1] + v[2] + v[3];
    int x = tsum;
#pragma unroll
    for (int d = 1; d < 64; d <<= 1) {
      int y = __shfl_up(x, d);
      if (lane >= d) x += y;
    }
    if (lane == 63) wsum[wv] = x;
    __syncthreads();
    if (wv == 0) {
      int y = (lane < 16) ? wsum[lane] : 0;
#pragma unroll
      for (int d = 1; d < 16; d <<= 1) {
        int z = __shfl_up(y, d);
        if (lane >= d) y += z;
      }
      if (lane < 16) wsum[lane] = y;
    }
    __syncthreads();
    int wbase = (wv > 0) ? wsum[wv - 1] : 0;
    int excl = carry_s + wbase + (x - tsum);
#pragma unroll
    for (int j = 0; j < 4; ++j) {
      int i = base_i + j;
      if (i < N) { rowptr[i] = excl; pos[i] = excl; }
      excl += v[j];
    }
    __syncthreads();
    if (t == 0) carry_s += wsum[15];
    __syncthreads();
  }
  if (t == 0) rowptr[N] = E;
}

__global__ __launch_bounds__(256) void fill_kernel(const int* __restrict__ src,
                                                   const int* __restrict__ dst,
                                                   int* __restrict__ pos,
                                                   int* __restrict__ colidx, int E) {
  int e = blockIdx.x * 256 + threadIdx.x;
  if (e < E) {
    int p = atomicAdd(&pos[dst[e]], 1);
    colidx[p] = src[e];
  }
}

__global__ __launch_bounds__(256) void norm_kernel(const int* __restrict__ deg,
                                                   float* __restrict__ n1,
                                                   float* __restrict__ n2, int N) {
  int i = blockIdx.x * 256 + threadIdx.x;
  if (i < N) {
    int di = deg[i];
    float d = (float)(di < 1 ? 1 : di);
    float r = 1.0f / sqrtf(d);
    n1[i] = r;
    n2[i] = r / d;
  }
}

// agg[i] = ( sum_{e in row i} h[col[e]] * n1[col[e]] ) * n2[i]
// 8-wide batched gather: 8 independent colidx loads, then 8 n1 + 8 h-row
// loads in flight per wave (latency hiding); tail via clamp+zero-weight.
__global__ __launch_bounds__(256) void agg_kernel(const float* __restrict__ h,
                                                  const int* __restrict__ rowptr,
                                                  const int* __restrict__ colidx,
                                                  const float* __restrict__ n1,
                                                  const float* __restrict__ n2,
                                                  float* __restrict__ agg, int N) {
  int wid = (blockIdx.x * 256 + threadIdx.x) >> 6;
  int lane = threadIdx.x & 63;
  if (wid >= N) return;
  int s = rowptr[wid], e = rowptr[wid + 1];
  const float2* h2 = (const float2*)h;
  float ax[4] = {0.f, 0.f, 0.f, 0.f};
  float ay[4] = {0.f, 0.f, 0.f, 0.f};
  for (int i = s; i < e; i += 8) {
    int c[8];
#pragma unroll
    for (int j = 0; j < 8; ++j) {
      int idx = i + j;
      c[j] = colidx[idx < e ? idx : e - 1];
    }
    float sc[8];
#pragma unroll
    for (int j = 0; j < 8; ++j) sc[j] = (i + j < e) ? n1[c[j]] : 0.f;
    float2 v[8];
#pragma unroll
    for (int j = 0; j < 8; ++j) v[j] = h2[(size_t)c[j] * 64 + lane];
#pragma unroll
    for (int j = 0; j < 8; ++j) {
      ax[j & 3] = fmaf(v[j].x, sc[j], ax[j & 3]);
      ay[j & 3] = fmaf(v[j].y, sc[j], ay[j & 3]);
    }
  }
  float m = n2[wid];
  float axs = (ax[0] + ax[1]) + (ax[2] + ax[3]);
  float ays = (ay[0] + ay[1]) + (ay[2] + ay[3]);
  ((float2*)agg)[(size_t)wid * 64 + lane] = make_float2(axs * m, ays * m);
}

// ---------------------------------------------------------------------------
// Weight prep: W[K][C] fp32 -> Wt_hi/lo[C][K] bf16 (transposed + split)
// ---------------------------------------------------------------------------
__global__ __launch_bounds__(256) void prep_w(const float* __restrict__ src,
                                              unsigned short* __restrict__ dh,
                                              unsigned short* __restrict__ dl,
                                              int K, int C) {
  int t = blockIdx.x * 256 + threadIdx.x;
  if (t >= K * C) return;
  int c = t / K, k = t - c * K;
  unsigned int h, l;
  split2(src[(size_t)k * C + c], h, l);
  dh[t] = (unsigned short)h;
  dl[t] = (unsigned short)l;
}

// ---------------------------------------------------------------------------
// Fused MFMA kernel. KIND 0: out = A@W1 + b1  (encoder, K=128)
// KIND 1: z = relu([A|A2] @ W1 + b1); out = A + relu(z @ W2 + b2)   (layer)
// Tile 128 rows x 128 cols, 512 threads = 8 waves (2 row-groups x 4 col-groups).
// Split-bf16: 3 MFMAs (hh, hl, lh) per fragment pair.
// LDS: As hi/lo [128][128] bf16 + Ws hi/lo [128 cols][128 k] bf16 = 128 KB,
// 16B chunks XOR-swizzled: chunk ^= (row & 7) (low 3 bits of chunk index).
// ---------------------------------------------------------------------------
template <int KIND>
__global__ __launch_bounds__(512, 2) void sage_mm(
    const float* __restrict__ A, const float* __restrict__ A2,
    const unsigned short* __restrict__ W1h, const unsigned short* __restrict__ W1l,
    const unsigned short* __restrict__ W2h, const unsigned short* __restrict__ W2l,
    const float* __restrict__ b1, const float* __restrict__ b2,
    float* __restrict__ out, int M) {
  __shared__ unsigned short AsH[128 * 128];
  __shared__ unsigned short AsL[128 * 128];
  __shared__ unsigned short WsH[128 * 128];
  __shared__ unsigned short WsL[128 * 128];

  const int t = threadIdx.x;
  const int lane = t & 63;
  const int w = t >> 6;
  const int rl = lane & 15, g = lane >> 4;
  const int rbase = (w >> 2) * 64;   // wave rows within tile
  const int cbase = (w & 3) * 32;    // wave cols within tile
  const int rowbase = blockIdx.x * 128;

  // stage full [128 cols][128 k] bf16 pair: 2048 16B-chunks, 4 per thread
  auto stageW = [&](const unsigned short* sh, const unsigned short* sl, int ldk,
                    int k0) {
#pragma unroll
    for (int j = 0; j < 4; ++j) {
      int ch = t * 4 + j;            // 0..2047
      int c = ch >> 4, cc = ch & 15; // col, 16B-chunk within col
      int off = c * 256 + ((cc ^ (c & 7)) << 4);
      *(int4*)((char*)WsH + off) = *(const int4*)(sh + (size_t)c * ldk + k0 + cc * 8);
      *(int4*)((char*)WsL + off) = *(const int4*)(sl + (size_t)c * ldk + k0 + cc * 8);
    }
  };

  auto stageA = [&](const float* __restrict__ src) {
    int r = t >> 2, kc = (t & 3) * 32;
    int grow = rowbase + r;
    const float4* s = (const float4*)(src + (size_t)grow * 128 + kc);
#pragma unroll
    for (int j = 0; j < 8; ++j) {
      float4 v = make_float4(0.f, 0.f, 0.f, 0.f);
      if (grow < M) v = s[j];
      unsigned int h0, l0, h1, l1, h2, l2, h3, l3;
      split2(v.x, h0, l0); split2(v.y, h1, l1);
      split2(v.z, h2, l2); split2(v.w, h3, l3);
      int off = r * 256 + ((2 * (kc + j * 4)) ^ ((r & 7) << 4));
      *(int2*)((char*)AsH + off) =
          make_int2((int)(h0 | (h1 << 16)), (int)(h2 | (h3 << 16)));
      *(int2*)((char*)AsL + off) =
          make_int2((int)(l0 | (l1 << 16)), (int)(l2 | (l3 << 16)));
    }
  };

  f32x4 acc[4][2];
  auto zacc = [&]() {
#pragma unroll
    for (int i = 0; i < 4; ++i)
#pragma unroll
      for (int j = 0; j < 2; ++j) {
        f32x4 z = {0.f, 0.f, 0.f, 0.f};
        acc[i][j] = z;
      }
  };

  auto kloop = [&]() {
#pragma unroll
    for (int ks = 0; ks < 4; ++ks) {
      short8 aH[4], aL[4], bH[2], bL[2];
#pragma unroll
      for (int fr = 0; fr < 4; ++fr) {
        int row = rbase + fr * 16 + rl;
        int off = row * 256 + (((ks * 4 + g) ^ (row & 7)) << 4);
        aH[fr] = *(const short8*)((const char*)AsH + off);
        aL[fr] = *(const short8*)((const char*)AsL + off);
      }
#pragma unroll
      for (int fc = 0; fc < 2; ++fc) {
        int col = cbase + fc * 16 + rl;
        int off = col * 256 + (((ks * 4 + g) ^ (col & 7)) << 4);
        bH[fc] = *(const short8*)((const char*)WsH + off);
        bL[fc] = *(const short8*)((const char*)WsL + off);
      }
#pragma unroll
      for (int fr = 0; fr < 4; ++fr)
#pragma unroll
        for (int fc = 0; fc < 2; ++fc) {
          acc[fr][fc] = __builtin_amdgcn_mfma_f32_16x16x32_bf16(
              aH[fr], bH[fc], acc[fr][fc], 0, 0, 0);
          acc[fr][fc] = __builtin_amdgcn_mfma_f32_16x16x32_bf16(
              aH[fr], bL[fc], acc[fr][fc], 0, 0, 0);
          acc[fr][fc] = __builtin_amdgcn_mfma_f32_16x16x32_bf16(
              aL[fr], bH[fc], acc[fr][fc], 0, 0, 0);
        }
    }
  };

  zacc();
  stageA(A);
  stageW(W1h, W1l, (KIND == 1) ? 256 : 128, 0);
  __syncthreads();
  kloop();

  if (KIND == 0) {
#pragma unroll
    for (int fc = 0; fc < 2; ++fc) {
      int col = cbase + fc * 16 + rl;
      float bb = b1[col];
#pragma unroll
      for (int fr = 0; fr < 4; ++fr)
#pragma unroll
        for (int q = 0; q < 4; ++q) {
          int row = rowbase + rbase + fr * 16 + g * 4 + q;
          if (row < M) out[(size_t)row * 128 + col] = acc[fr][fc][q] + bb;
        }
    }
    return;
  }

  __syncthreads();
  stageA(A2);
  stageW(W1h, W1l, 256, 128);
  __syncthreads();
  kloop();
  __syncthreads();  // everyone done reading As/Ws

  // z = relu(acc + b1) -> As (hi/lo, swizzled); stage W2
#pragma unroll
  for (int fc = 0; fc < 2; ++fc) {
    int col = cbase + fc * 16 + rl;
    float bb = b1[col];
#pragma unroll
    for (int fr = 0; fr < 4; ++fr)
#pragma unroll
      for (int q = 0; q < 4; ++q) {
        int row = rbase + fr * 16 + g * 4 + q;  // tile-relative
        float z = fmaxf(acc[fr][fc][q] + bb, 0.f);
        unsigned int h, l;
        split2(z, h, l);
        int off = row * 256 + ((2 * col) ^ ((row & 7) << 4));
        *(unsigned short*)((char*)AsH + off) = (unsigned short)h;
        *(unsigned short*)((char*)AsL + off) = (unsigned short)l;
      }
  }
  stageW(W2h, W2l, 128, 0);
  zacc();
  __syncthreads();
  kloop();

  // out = A + relu(acc + b2)
#pragma unroll
  for (int fc = 0; fc < 2; ++fc) {
    int col = cbase + fc * 16 + rl;
    float bb = b2[col];
#pragma unroll
    for (int fr = 0; fr < 4; ++fr)
#pragma unroll
      for (int q = 0; q < 4; ++q) {
        int row = rowbase + rbase + fr * 16 + g * 4 + q;
        if (row < M) {
          float z = fmaxf(acc[fr][fc][q] + bb, 0.f);
          out[(size_t)row * 128 + col] = A[(size_t)row * 128 + col] + z;
        }
      }
  }
}

// ---------------------------------------------------------------------------
// Pooling + readout
// ---------------------------------------------------------------------------
__global__ __launch_bounds__(256) void pool_partial(const float* __restrict__ h,
                                                    float* __restrict__ partial,
                                                    int N) {
  int col = threadIdx.x & 127;
  int stream = blockIdx.x * 2 + (threadIdx.x >> 7);
  float s = 0.f;
  for (int r = stream; r < N; r += 512) s += h[(size_t)r * 128 + col];
  partial[stream * 128 + col] = s;
}

__global__ __launch_bounds__(256) void readout_kernel(
    const float* __restrict__ partial, const float* __restrict__ rW1,
    const float* __restrict__ rb1, const float* __restrict__ rW2,
    const float* __restrict__ rb2, const float* __restrict__ rW3,
    const float* __restrict__ rb3, float* __restrict__ outp, int N) {
  __shared__ float pooled[128];
  __shared__ float x1[64];
  __shared__ float x2[32];
  int t = threadIdx.x;
  if (t < 128) {
    float s = 0.f;
    for (int i = 0; i < 512; ++i) s += partial[i * 128 + t];
    pooled[t] = s / (float)N;
  }
  __syncthreads();
  if (t < 64) {
    float s = rb1[t];
    for (int k = 0; k < 128; ++k) s = fmaf(pooled[k], rW1[k * 64 + t], s);
    x1[t] = fmaxf(s, 0.f);
  }
  __syncthreads();
  if (t < 32) {
    float s = rb2[t];
    for (int k = 0; k < 64; ++k) s = fmaf(x1[k], rW2[k * 32 + t], s);
    x2[t] = fmaxf(s, 0.f);
  }
  __syncthreads();
  if (t < 10) {
    float s = rb3[t];
    for (int k = 0; k < 32; ++k) s = fmaf(x2[k], rW3[k * 10 + t], s);
    outp[t] = s;
  }
}

extern "C" void kernel_launch(void* const* d_in, const int* in_sizes, int n_in,
                              void* d_out, int out_size, void* d_ws, size_t ws_size,
                              hipStream_t stream) {
  const float* h_in  = (const float*)d_in[0];
  const int*   src   = (const int*)d_in[1];
  const int*   dst   = (const int*)d_in[2];
  const float* enc_W = (const float*)d_in[3];
  const float* enc_b = (const float*)d_in[4];
  const float* W1    = (const float*)d_in[5];
  const float* b1    = (const float*)d_in[6];
  const float* W2    = (const float*)d_in[7];
  const float* b2    = (const float*)d_in[8];
  const float* rW1   = (const float*)d_in[9];
  const float* rb1   = (const float*)d_in[10];
  const float* rW2   = (const float*)d_in[11];
  const float* rb2   = (const float*)d_in[12];
  const float* rW3   = (const float*)d_in[13];
  const float* rb3   = (const float*)d_in[14];

  const int N = in_sizes[0] / 128;
  const int E = in_sizes[1];
  const int L = in_sizes[6] / 128;

  char* ws = (char*)d_ws;
  size_t off = 0;
  auto alloc = [&](size_t bytes) {
    char* p = ws + off;
    off = (off + bytes + 511) & ~(size_t)511;
    return p;
  };
  float* h       = (float*)alloc((size_t)N * 128 * 4);
  float* agg     = (float*)alloc((size_t)N * 128 * 4);
  int* deg       = (int*)alloc((size_t)N * 4);
  int* rowptr    = (int*)alloc((size_t)(N + 1) * 4);
  int* pos       = (int*)alloc((size_t)N * 4);
  int* colidx    = (int*)alloc((size_t)E * 4);
  float* n1      = (float*)alloc((size_t)N * 4);
  float* n2      = (float*)alloc((size_t)N * 4);
  float* partial = (float*)alloc((size_t)512 * 128 * 4);
  unsigned short* encWh = (unsigned short*)alloc(16384 * 2);
  unsigned short* encWl = (unsigned short*)alloc(16384 * 2);
  unsigned short* W1th  = (unsigned short*)alloc((size_t)L * 32768 * 2);
  unsigned short* W1tl  = (unsigned short*)alloc((size_t)L * 32768 * 2);
  unsigned short* W2th  = (unsigned short*)alloc((size_t)L * 16384 * 2);
  unsigned short* W2tl  = (unsigned short*)alloc((size_t)L * 16384 * 2);
  (void)ws_size; (void)n_in; (void)out_size;

  hipMemsetAsync(deg, 0, (size_t)N * 4, stream);
  deg_kernel<<<(E + 255) / 256, 256, 0, stream>>>(dst, deg, E);
  scan_kernel<<<1, 1024, 0, stream>>>(deg, rowptr, pos, N, E);
  fill_kernel<<<(E + 255) / 256, 256, 0, stream>>>(src, dst, pos, colidx, E);
  norm_kernel<<<(N + 255) / 256, 256, 0, stream>>>(deg, n1, n2, N);

  // weight prep (transpose + hi/lo split)
  prep_w<<<64, 256, 0, stream>>>(enc_W, encWh, encWl, 128, 128);
  for (int l = 0; l < L; ++l) {
    prep_w<<<128, 256, 0, stream>>>(W1 + (size_t)l * 32768,
                                    W1th + (size_t)l * 32768,
                                    W1tl + (size_t)l * 32768, 256, 128);
    prep_w<<<64, 256, 0, stream>>>(W2 + (size_t)l * 16384,
                                   W2th + (size_t)l * 16384,
                                   W2tl + (size_t)l * 16384, 128, 128);
  }

  const int gblocks = (N + 127) / 128;
  sage_mm<0><<<gblocks, 512, 0, stream>>>(h_in, nullptr, encWh, encWl, nullptr,
                                          nullptr, enc_b, nullptr, h, N);
  for (int l = 0; l < L; ++l) {
    agg_kernel<<<(N + 3) / 4, 256, 0, stream>>>(h, rowptr, colidx, n1, n2, agg, N);
    sage_mm<1><<<gblocks, 512, 0, stream>>>(
        h, agg, W1th + (size_t)l * 32768, W1tl + (size_t)l * 32768,
        W2th + (size_t)l * 16384, W2tl + (size_t)l * 16384,
        b1 + l * 128, b2 + l * 128, h, N);
  }
  pool_partial<<<256, 256, 0, stream>>>(h, partial, N);
  readout_kernel<<<1, 256, 0, stream>>>(partial, rW1, rb1, rW2, rb2, rW3, rb3,
                                        (float*)d_out, N);
}

// Round 8
// 917.269 us; speedup vs baseline: 2.3444x; 1.3716x over previous
//
#include <hip/hip_runtime.h>
#include <hip/hip_fp16.h>
#include <math.h>

typedef short short8 __attribute__((ext_vector_type(8)));
typedef float f32x4 __attribute__((ext_vector_type(4)));

#define DEV static __device__ __forceinline__

// ---- fp32 -> (hi, lo) bf16 split: x ~= hi + lo, |err| ~ 4e-6 |x| -----------
DEV unsigned int bf16h(float x) {
  unsigned int u = __float_as_uint(x);
  return (u + 0x7FFFu + ((u >> 16) & 1u)) >> 16;
}
DEV void split2(float x, unsigned int& h, unsigned int& l) {
  h = bf16h(x);
  float hf = __uint_as_float(h << 16);
  l = bf16h(x - hf);
}

// ---------------------------------------------------------------------------
// CSR build via 128-row bucket sort (cross-XCD-write-friendly).
// A: per-(block,bucket) histogram  S: scans  B: scatter pairs into contiguous
// per-(block,bucket) runs  C: per-bucket exact sort -> rowptr/colidx/n1/n2
// ---------------------------------------------------------------------------
__global__ __launch_bounds__(256) void bucketA(const int* __restrict__ dst,
                                               int* __restrict__ histG,
                                               int E, int chunk, int NB) {
  __shared__ int lh[1024];
  const int t = threadIdx.x;
  for (int i = t; i < NB; i += 256) lh[i] = 0;
  __syncthreads();
  int s = blockIdx.x * chunk;
  int e = s + chunk; if (e > E) e = E;
  for (int i = s + t; i < e; i += 256) atomicAdd(&lh[dst[i] >> 7], 1);
  __syncthreads();
  for (int b = t; b < NB; b += 256) histG[b * 64 + blockIdx.x] = lh[b];
}

__global__ __launch_bounds__(1024) void bucketS(int* __restrict__ histG,
                                                int* __restrict__ bucketStart,
                                                int NB) {
  __shared__ int btot[1024];
  __shared__ int wsum[16];
  const int t = threadIdx.x, lane = t & 63, wv = t >> 6;
  // per-bucket exclusive scan over the 64 block counts
  for (int b = wv; b < NB; b += 16) {
    int v = histG[b * 64 + lane];
    int x = v;
#pragma unroll
    for (int d = 1; d < 64; d <<= 1) {
      int y = __shfl_up(x, d);
      if (lane >= d) x += y;
    }
    histG[b * 64 + lane] = x - v;   // exclusive prefix within bucket
    if (lane == 63) btot[b] = x;    // bucket total
  }
  __syncthreads();
  // exclusive scan across buckets (NB <= 1024)
  int v = (t < NB) ? btot[t] : 0;
  int x = v;
#pragma unroll
  for (int d = 1; d < 64; d <<= 1) {
    int y = __shfl_up(x, d);
    if (lane >= d) x += y;
  }
  if (lane == 63) wsum[wv] = x;
  __syncthreads();
  if (wv == 0) {
    int y = (lane < 16) ? wsum[lane] : 0;
#pragma unroll
    for (int d = 1; d < 16; d <<= 1) {
      int z = __shfl_up(y, d);
      if (lane >= d) y += z;
    }
    if (lane < 16) wsum[lane] = y;
  }
  __syncthreads();
  int wbase = (wv > 0) ? wsum[wv - 1] : 0;
  int incl = wbase + x;
  if (t < NB) bucketStart[t] = incl - v;
  if (t == NB - 1) bucketStart[NB] = incl;  // == E
}

__global__ __launch_bounds__(256) void bucketB(const int* __restrict__ src,
                                               const int* __restrict__ dstA,
                                               const int* __restrict__ histG,
                                               const int* __restrict__ bucketStart,
                                               int2* __restrict__ pairs,
                                               int E, int chunk, int NB) {
  __shared__ int lbase[1024];
  __shared__ int lcnt[1024];
  const int t = threadIdx.x;
  for (int i = t; i < NB; i += 256) {
    lbase[i] = bucketStart[i] + histG[i * 64 + blockIdx.x];
    lcnt[i] = 0;
  }
  __syncthreads();
  int s = blockIdx.x * chunk;
  int e = s + chunk; if (e > E) e = E;
  for (int i = s + t; i < e; i += 256) {
    int d = dstA[i];
    int b = d >> 7;
    int r = atomicAdd(&lcnt[b], 1);
    pairs[lbase[b] + r] = make_int2(src[i], d);
  }
}

__global__ __launch_bounds__(256) void bucketC(const int2* __restrict__ pairs,
                                               const int* __restrict__ bucketStart,
                                               int* __restrict__ rowptr,
                                               int* __restrict__ colidx,
                                               float* __restrict__ n1,
                                               float* __restrict__ n2,
                                               int N, int E) {
  __shared__ int degs[128];
  __shared__ int incl[128];
  __shared__ int cur[128];
  const int t = threadIdx.x, lane = t & 63;
  const int b = blockIdx.x;
  const int lo = b << 7;
  const int s0 = bucketStart[b], s1 = bucketStart[b + 1];
  if (t < 128) degs[t] = 0;
  __syncthreads();
  for (int i = s0 + t; i < s1; i += 256) atomicAdd(&degs[pairs[i].y - lo], 1);
  __syncthreads();
  int d = 0, x = 0;
  if (t < 128) {
    d = degs[t];
    x = d;
#pragma unroll
    for (int dd = 1; dd < 64; dd <<= 1) {
      int y = __shfl_up(x, dd);
      if (lane >= dd) x += y;
    }
    incl[t] = x;
  }
  __syncthreads();
  if (t >= 64 && t < 128) incl[t] += incl[63];
  __syncthreads();
  if (t < 128) {
    int excl = incl[t] - d;
    int row = lo + t;
    if (row < N) {
      rowptr[row] = s0 + excl;
      int dd2 = d < 1 ? 1 : d;
      float fd = (float)dd2;
      float r = 1.0f / sqrtf(fd);
      n1[row] = r;
      n2[row] = r / fd;
    }
    cur[t] = excl;
  }
  __syncthreads();
  for (int i = s0 + t; i < s1; i += 256) {
    int2 p = pairs[i];
    int off = atomicAdd(&cur[p.y - lo], 1);
    colidx[s0 + off] = p.x;
  }
  if (b == 0 && t == 0) rowptr[N] = E;
}

// ---------------------------------------------------------------------------
// agg[i] = ( sum_{e in row i} h16[col[e]] ) * n2[i]   (n1 folded into h16)
// 8-wide batched gather, 256B fp16 rows.
// ---------------------------------------------------------------------------
__global__ __launch_bounds__(256) void agg_kernel(const __half* __restrict__ h16,
                                                  const int* __restrict__ rowptr,
                                                  const int* __restrict__ colidx,
                                                  const float* __restrict__ n2,
                                                  float* __restrict__ agg, int N) {
  int wid = (blockIdx.x * 256 + threadIdx.x) >> 6;
  int lane = threadIdx.x & 63;
  if (wid >= N) return;
  int s = rowptr[wid], e = rowptr[wid + 1];
  const __half2* h2 = (const __half2*)h16;
  float ax[4] = {0.f, 0.f, 0.f, 0.f};
  float ay[4] = {0.f, 0.f, 0.f, 0.f};
  for (int i = s; i < e; i += 8) {
    int c[8];
#pragma unroll
    for (int j = 0; j < 8; ++j) {
      int idx = i + j;
      c[j] = colidx[idx < e ? idx : e - 1];
    }
    __half2 v[8];
#pragma unroll
    for (int j = 0; j < 8; ++j) v[j] = h2[(size_t)c[j] * 64 + lane];
#pragma unroll
    for (int j = 0; j < 8; ++j) {
      float2 f = __half22float2(v[j]);
      bool ok = (i + j) < e;
      ax[j & 3] += ok ? f.x : 0.f;
      ay[j & 3] += ok ? f.y : 0.f;
    }
  }
  float m = n2[wid];
  float axs = (ax[0] + ax[1]) + (ax[2] + ax[3]);
  float ays = (ay[0] + ay[1]) + (ay[2] + ay[3]);
  ((float2*)agg)[(size_t)wid * 64 + lane] = make_float2(axs * m, ays * m);
}

// ---------------------------------------------------------------------------
// Weight prep, single launch: enc (K=128) + L x W1 (K=256) + L x W2 (K=128)
// dest layout [C][K] hi/lo bf16 (transposed + split)
// ---------------------------------------------------------------------------
__global__ __launch_bounds__(256) void prep_all(
    const float* __restrict__ encW, const float* __restrict__ W1,
    const float* __restrict__ W2, unsigned short* __restrict__ encWh,
    unsigned short* __restrict__ encWl, unsigned short* __restrict__ W1th,
    unsigned short* __restrict__ W1tl, unsigned short* __restrict__ W2th,
    unsigned short* __restrict__ W2tl, int L) {
  int t = blockIdx.x * 256 + threadIdx.x;
  const int n1e = 16384;
  const int n2e = n1e + L * 32768;
  const int n3e = n2e + L * 16384;
  unsigned int h, l;
  if (t < n1e) {
    int c = t >> 7, k = t & 127;
    split2(encW[k * 128 + c], h, l);
    encWh[t] = (unsigned short)h; encWl[t] = (unsigned short)l;
  } else if (t < n2e) {
    int u = t - n1e;
    int ll = u >> 15, w = u & 32767;
    int c = w >> 8, k = w & 255;
    split2(W1[(size_t)ll * 32768 + k * 128 + c], h, l);
    W1th[u] = (unsigned short)h; W1tl[u] = (unsigned short)l;
  } else if (t < n3e) {
    int u = t - n2e;
    int ll = u >> 14, w = u & 16383;
    int c = w >> 7, k = w & 127;
    split2(W2[(size_t)ll * 16384 + k * 128 + c], h, l);
    W2th[u] = (unsigned short)h; W2tl[u] = (unsigned short)l;
  }
}

// ---------------------------------------------------------------------------
// Fused MFMA kernel. KIND 0: out = A@W1 + b1 (encoder). KIND 1: layer fused.
// Also emits h16[row] = fp16(out[row] * n1[row]) for the next aggregation.
// ---------------------------------------------------------------------------
template <int KIND>
__global__ __launch_bounds__(512, 2) void sage_mm(
    const float* __restrict__ A, const float* __restrict__ A2,
    const unsigned short* __restrict__ W1h, const unsigned short* __restrict__ W1l,
    const unsigned short* __restrict__ W2h, const unsigned short* __restrict__ W2l,
    const float* __restrict__ b1, const float* __restrict__ b2,
    const float* __restrict__ n1, float* __restrict__ out,
    __half* __restrict__ h16, int M) {
  __shared__ unsigned short AsH[128 * 128];
  __shared__ unsigned short AsL[128 * 128];
  __shared__ unsigned short WsH[128 * 128];
  __shared__ unsigned short WsL[128 * 128];

  const int t = threadIdx.x;
  const int lane = t & 63;
  const int w = t >> 6;
  const int rl = lane & 15, g = lane >> 4;
  const int rbase = (w >> 2) * 64;
  const int cbase = (w & 3) * 32;
  const int rowbase = blockIdx.x * 128;

  auto stageW = [&](const unsigned short* sh, const unsigned short* sl, int ldk,
                    int k0) {
#pragma unroll
    for (int j = 0; j < 4; ++j) {
      int ch = t * 4 + j;
      int c = ch >> 4, cc = ch & 15;
      int off = c * 256 + ((cc ^ (c & 7)) << 4);
      *(int4*)((char*)WsH + off) = *(const int4*)(sh + (size_t)c * ldk + k0 + cc * 8);
      *(int4*)((char*)WsL + off) = *(const int4*)(sl + (size_t)c * ldk + k0 + cc * 8);
    }
  };

  auto stageA = [&](const float* __restrict__ src) {
    int r = t >> 2, kc = (t & 3) * 32;
    int grow = rowbase + r;
    const float4* s = (const float4*)(src + (size_t)grow * 128 + kc);
#pragma unroll
    for (int j = 0; j < 8; ++j) {
      float4 v = make_float4(0.f, 0.f, 0.f, 0.f);
      if (grow < M) v = s[j];
      unsigned int h0, l0, h1, l1, h2, l2, h3, l3;
      split2(v.x, h0, l0); split2(v.y, h1, l1);
      split2(v.z, h2, l2); split2(v.w, h3, l3);
      int off = r * 256 + ((2 * (kc + j * 4)) ^ ((r & 7) << 4));
      *(int2*)((char*)AsH + off) =
          make_int2((int)(h0 | (h1 << 16)), (int)(h2 | (h3 << 16)));
      *(int2*)((char*)AsL + off) =
          make_int2((int)(l0 | (l1 << 16)), (int)(l2 | (l3 << 16)));
    }
  };

  f32x4 acc[4][2];
  auto zacc = [&]() {
#pragma unroll
    for (int i = 0; i < 4; ++i)
#pragma unroll
      for (int j = 0; j < 2; ++j) {
        f32x4 z = {0.f, 0.f, 0.f, 0.f};
        acc[i][j] = z;
      }
  };

  auto kloop = [&]() {
#pragma unroll
    for (int ks = 0; ks < 4; ++ks) {
      short8 aH[4], aL[4], bH[2], bL[2];
#pragma unroll
      for (int fr = 0; fr < 4; ++fr) {
        int row = rbase + fr * 16 + rl;
        int off = row * 256 + (((ks * 4 + g) ^ (row & 7)) << 4);
        aH[fr] = *(const short8*)((const char*)AsH + off);
        aL[fr] = *(const short8*)((const char*)AsL + off);
      }
#pragma unroll
      for (int fc = 0; fc < 2; ++fc) {
        int col = cbase + fc * 16 + rl;
        int off = col * 256 + (((ks * 4 + g) ^ (col & 7)) << 4);
        bH[fc] = *(const short8*)((const char*)WsH + off);
        bL[fc] = *(const short8*)((const char*)WsL + off);
      }
#pragma unroll
      for (int fr = 0; fr < 4; ++fr)
#pragma unroll
        for (int fc = 0; fc < 2; ++fc) {
          acc[fr][fc] = __builtin_amdgcn_mfma_f32_16x16x32_bf16(
              aH[fr], bH[fc], acc[fr][fc], 0, 0, 0);
          acc[fr][fc] = __builtin_amdgcn_mfma_f32_16x16x32_bf16(
              aH[fr], bL[fc], acc[fr][fc], 0, 0, 0);
          acc[fr][fc] = __builtin_amdgcn_mfma_f32_16x16x32_bf16(
              aL[fr], bH[fc], acc[fr][fc], 0, 0, 0);
        }
    }
  };

  zacc();
  stageA(A);
  stageW(W1h, W1l, (KIND == 1) ? 256 : 128, 0);
  __syncthreads();
  kloop();

  if (KIND == 0) {
#pragma unroll
    for (int fc = 0; fc < 2; ++fc) {
      int col = cbase + fc * 16 + rl;
      float bb = b1[col];
#pragma unroll
      for (int fr = 0; fr < 4; ++fr)
#pragma unroll
        for (int q = 0; q < 4; ++q) {
          int row = rowbase + rbase + fr * 16 + g * 4 + q;
          if (row < M) {
            float val = acc[fr][fc][q] + bb;
            out[(size_t)row * 128 + col] = val;
            h16[(size_t)row * 128 + col] = __float2half(val * n1[row]);
          }
        }
    }
    return;
  }

  __syncthreads();
  stageA(A2);
  stageW(W1h, W1l, 256, 128);
  __syncthreads();
  kloop();
  __syncthreads();

  // z = relu(acc + b1) -> As (hi/lo, swizzled); stage W2
#pragma unroll
  for (int fc = 0; fc < 2; ++fc) {
    int col = cbase + fc * 16 + rl;
    float bb = b1[col];
#pragma unroll
    for (int fr = 0; fr < 4; ++fr)
#pragma unroll
      for (int q = 0; q < 4; ++q) {
        int row = rbase + fr * 16 + g * 4 + q;
        float z = fmaxf(acc[fr][fc][q] + bb, 0.f);
        unsigned int h, l;
        split2(z, h, l);
        int off = row * 256 + ((2 * col) ^ ((row & 7) << 4));
        *(unsigned short*)((char*)AsH + off) = (unsigned short)h;
        *(unsigned short*)((char*)AsL + off) = (unsigned short)l;
      }
  }
  stageW(W2h, W2l, 128, 0);
  zacc();
  __syncthreads();
  kloop();

  // out = A + relu(acc + b2);  h16 = fp16(out * n1)
#pragma unroll
  for (int fc = 0; fc < 2; ++fc) {
    int col = cbase + fc * 16 + rl;
    float bb = b2[col];
#pragma unroll
    for (int fr = 0; fr < 4; ++fr)
#pragma unroll
      for (int q = 0; q < 4; ++q) {
        int row = rowbase + rbase + fr * 16 + g * 4 + q;
        if (row < M) {
          float z = fmaxf(acc[fr][fc][q] + bb, 0.f);
          float val = A[(size_t)row * 128 + col] + z;
          out[(size_t)row * 128 + col] = val;
          h16[(size_t)row * 128 + col] = __float2half(val * n1[row]);
        }
      }
  }
}

// ---------------------------------------------------------------------------
// Pooling + readout
// ---------------------------------------------------------------------------
__global__ __launch_bounds__(256) void pool_partial(const float* __restrict__ h,
                                                    float* __restrict__ partial,
                                                    int N) {
  int col = threadIdx.x & 127;
  int stream = blockIdx.x * 2 + (threadIdx.x >> 7);
  float s = 0.f;
  for (int r = stream; r < N; r += 512) s += h[(size_t)r * 128 + col];
  partial[stream * 128 + col] = s;
}

__global__ __launch_bounds__(256) void readout_kernel(
    const float* __restrict__ partial, const float* __restrict__ rW1,
    const float* __restrict__ rb1, const float* __restrict__ rW2,
    const float* __restrict__ rb2, const float* __restrict__ rW3,
    const float* __restrict__ rb3, float* __restrict__ outp, int N) {
  __shared__ float pooled[128];
  __shared__ float x1[64];
  __shared__ float x2[32];
  int t = threadIdx.x;
  if (t < 128) {
    float s = 0.f;
    for (int i = 0; i < 512; ++i) s += partial[i * 128 + t];
    pooled[t] = s / (float)N;
  }
  __syncthreads();
  if (t < 64) {
    float s = rb1[t];
    for (int k = 0; k < 128; ++k) s = fmaf(pooled[k], rW1[k * 64 + t], s);
    x1[t] = fmaxf(s, 0.f);
  }
  __syncthreads();
  if (t < 32) {
    float s = rb2[t];
    for (int k = 0; k < 64; ++k) s = fmaf(x1[k], rW2[k * 32 + t], s);
    x2[t] = fmaxf(s, 0.f);
  }
  __syncthreads();
  if (t < 10) {
    float s = rb3[t];
    for (int k = 0; k < 32; ++k) s = fmaf(x2[k], rW3[k * 10 + t], s);
    outp[t] = s;
  }
}

extern "C" void kernel_launch(void* const* d_in, const int* in_sizes, int n_in,
                              void* d_out, int out_size, void* d_ws, size_t ws_size,
                              hipStream_t stream) {
  const float* h_in  = (const float*)d_in[0];
  const int*   src   = (const int*)d_in[1];
  const int*   dst   = (const int*)d_in[2];
  const float* enc_W = (const float*)d_in[3];
  const float* enc_b = (const float*)d_in[4];
  const float* W1    = (const float*)d_in[5];
  const float* b1    = (const float*)d_in[6];
  const float* W2    = (const float*)d_in[7];
  const float* b2    = (const float*)d_in[8];
  const float* rW1   = (const float*)d_in[9];
  const float* rb1   = (const float*)d_in[10];
  const float* rW2   = (const float*)d_in[11];
  const float* rb2   = (const float*)d_in[12];
  const float* rW3   = (const float*)d_in[13];
  const float* rb3   = (const float*)d_in[14];

  const int N = in_sizes[0] / 128;
  const int E = in_sizes[1];
  const int L = in_sizes[6] / 128;
  const int NB = (N + 127) >> 7;          // 128-row buckets
  const int chunk = (E + 63) / 64;        // 64 blocks for passes A/B

  char* ws = (char*)d_ws;
  size_t off = 0;
  auto alloc = [&](size_t bytes) {
    char* p = ws + off;
    off = (off + bytes + 511) & ~(size_t)511;
    return p;
  };
  float* h        = (float*)alloc((size_t)N * 128 * 4);
  float* agg      = (float*)alloc((size_t)N * 128 * 4);
  __half* h16     = (__half*)alloc((size_t)N * 128 * 2);
  int* rowptr     = (int*)alloc((size_t)(N + 1) * 4);
  int* colidx     = (int*)alloc((size_t)E * 4);
  float* n1       = (float*)alloc((size_t)N * 4);
  float* n2       = (float*)alloc((size_t)N * 4);
  int* histG      = (int*)alloc((size_t)NB * 64 * 4);
  int* bucketStart= (int*)alloc((size_t)(NB + 1) * 4);
  float* partial  = (float*)alloc((size_t)512 * 128 * 4);
  unsigned short* encWh = (unsigned short*)alloc(16384 * 2);
  unsigned short* encWl = (unsigned short*)alloc(16384 * 2);
  unsigned short* W1th  = (unsigned short*)alloc((size_t)L * 32768 * 2);
  unsigned short* W1tl  = (unsigned short*)alloc((size_t)L * 32768 * 2);
  unsigned short* W2th  = (unsigned short*)alloc((size_t)L * 16384 * 2);
  unsigned short* W2tl  = (unsigned short*)alloc((size_t)L * 16384 * 2);
  int2* pairs = (int2*)agg;  // alias: pairs live only before first agg write
  (void)ws_size; (void)n_in; (void)out_size;

  // weight prep (one launch)
  {
    int tot = 16384 + L * 32768 + L * 16384;
    prep_all<<<(tot + 255) / 256, 256, 0, stream>>>(
        enc_W, W1, W2, encWh, encWl, W1th, W1tl, W2th, W2tl, L);
  }

  // CSR build
  bucketA<<<64, 256, 0, stream>>>(dst, histG, E, chunk, NB);
  bucketS<<<1, 1024, 0, stream>>>(histG, bucketStart, NB);
  bucketB<<<64, 256, 0, stream>>>(src, dst, histG, bucketStart, pairs, E, chunk, NB);
  bucketC<<<NB, 256, 0, stream>>>(pairs, bucketStart, rowptr, colidx, n1, n2, N, E);

  const int gblocks = (N + 127) / 128;
  sage_mm<0><<<gblocks, 512, 0, stream>>>(h_in, nullptr, encWh, encWl, nullptr,
                                          nullptr, enc_b, nullptr, n1, h, h16, N);
  for (int l = 0; l < L; ++l) {
    agg_kernel<<<(N + 3) / 4, 256, 0, stream>>>(h16, rowptr, colidx, n2, agg, N);
    sage_mm<1><<<gblocks, 512, 0, stream>>>(
        h, agg, W1th + (size_t)l * 32768, W1tl + (size_t)l * 32768,
        W2th + (size_t)l * 16384, W2tl + (size_t)l * 16384,
        b1 + l * 128, b2 + l * 128, n1, h, h16, N);
  }
  pool_partial<<<256, 256, 0, stream>>>(h, partial, N);
  readout_kernel<<<1, 256, 0, stream>>>(partial, rW1, rb1, rW2, rb2, rW3, rb3,
                                        (float*)d_out, N);
}

// Round 9
// 787.817 us; speedup vs baseline: 2.7297x; 1.1643x over previous
//
#include <hip/hip_runtime.h>
#include <hip/hip_fp16.h>
#include <math.h>

typedef short short8 __attribute__((ext_vector_type(8)));
typedef float f32x4 __attribute__((ext_vector_type(4)));

#define DEV static __device__ __forceinline__

// ---- fp32 -> (hi, lo) bf16 split: x ~= hi + lo, |err| ~ 4e-6 |x| -----------
DEV unsigned int bf16h(float x) {
  unsigned int u = __float_as_uint(x);
  return (u + 0x7FFFu + ((u >> 16) & 1u)) >> 16;
}
DEV void split2(float x, unsigned int& h, unsigned int& l) {
  h = bf16h(x);
  float hf = __uint_as_float(h << 16);
  l = bf16h(x - hf);
}

// ---------------------------------------------------------------------------
// CSR build via 128-row bucket sort (cross-XCD-write-friendly).
// ---------------------------------------------------------------------------
__global__ __launch_bounds__(256) void bucketA(const int* __restrict__ dst,
                                               int* __restrict__ histG,
                                               int E, int chunk, int NB) {
  __shared__ int lh[1024];
  const int t = threadIdx.x;
  for (int i = t; i < NB; i += 256) lh[i] = 0;
  __syncthreads();
  int s = blockIdx.x * chunk;
  int e = s + chunk; if (e > E) e = E;
  for (int i = s + t; i < e; i += 256) atomicAdd(&lh[dst[i] >> 7], 1);
  __syncthreads();
  for (int b = t; b < NB; b += 256) histG[b * 64 + blockIdx.x] = lh[b];
}

__global__ __launch_bounds__(1024) void bucketS(int* __restrict__ histG,
                                                int* __restrict__ bucketStart,
                                                int NB) {
  __shared__ int btot[1024];
  __shared__ int wsum[16];
  const int t = threadIdx.x, lane = t & 63, wv = t >> 6;
  for (int b = wv; b < NB; b += 16) {
    int v = histG[b * 64 + lane];
    int x = v;
#pragma unroll
    for (int d = 1; d < 64; d <<= 1) {
      int y = __shfl_up(x, d);
      if (lane >= d) x += y;
    }
    histG[b * 64 + lane] = x - v;
    if (lane == 63) btot[b] = x;
  }
  __syncthreads();
  int v = (t < NB) ? btot[t] : 0;
  int x = v;
#pragma unroll
  for (int d = 1; d < 64; d <<= 1) {
    int y = __shfl_up(x, d);
    if (lane >= d) x += y;
  }
  if (lane == 63) wsum[wv] = x;
  __syncthreads();
  if (wv == 0) {
    int y = (lane < 16) ? wsum[lane] : 0;
#pragma unroll
    for (int d = 1; d < 16; d <<= 1) {
      int z = __shfl_up(y, d);
      if (lane >= d) y += z;
    }
    if (lane < 16) wsum[lane] = y;
  }
  __syncthreads();
  int wbase = (wv > 0) ? wsum[wv - 1] : 0;
  int incl = wbase + x;
  if (t < NB) bucketStart[t] = incl - v;
  if (t == NB - 1) bucketStart[NB] = incl;
}

__global__ __launch_bounds__(256) void bucketB(const int* __restrict__ src,
                                               const int* __restrict__ dstA,
                                               const int* __restrict__ histG,
                                               const int* __restrict__ bucketStart,
                                               int2* __restrict__ pairs,
                                               int E, int chunk, int NB) {
  __shared__ int lbase[1024];
  __shared__ int lcnt[1024];
  const int t = threadIdx.x;
  for (int i = t; i < NB; i += 256) {
    lbase[i] = bucketStart[i] + histG[i * 64 + blockIdx.x];
    lcnt[i] = 0;
  }
  __syncthreads();
  int s = blockIdx.x * chunk;
  int e = s + chunk; if (e > E) e = E;
  for (int i = s + t; i < e; i += 256) {
    int d = dstA[i];
    int b = d >> 7;
    int r = atomicAdd(&lcnt[b], 1);
    pairs[lbase[b] + r] = make_int2(src[i], d);
  }
}

__global__ __launch_bounds__(256) void bucketC(const int2* __restrict__ pairs,
                                               const int* __restrict__ bucketStart,
                                               int* __restrict__ rowptr,
                                               int* __restrict__ colidx,
                                               float* __restrict__ n1,
                                               float* __restrict__ n2,
                                               int N, int E) {
  __shared__ int degs[128];
  __shared__ int incl[128];
  __shared__ int cur[128];
  const int t = threadIdx.x, lane = t & 63;
  const int b = blockIdx.x;
  const int lo = b << 7;
  const int s0 = bucketStart[b], s1 = bucketStart[b + 1];
  if (t < 128) degs[t] = 0;
  __syncthreads();
  for (int i = s0 + t; i < s1; i += 256) atomicAdd(&degs[pairs[i].y - lo], 1);
  __syncthreads();
  int d = 0, x = 0;
  if (t < 128) {
    d = degs[t];
    x = d;
#pragma unroll
    for (int dd = 1; dd < 64; dd <<= 1) {
      int y = __shfl_up(x, dd);
      if (lane >= dd) x += y;
    }
    incl[t] = x;
  }
  __syncthreads();
  if (t >= 64 && t < 128) incl[t] += incl[63];
  __syncthreads();
  if (t < 128) {
    int excl = incl[t] - d;
    int row = lo + t;
    if (row < N) {
      rowptr[row] = s0 + excl;
      int dd2 = d < 1 ? 1 : d;
      float fd = (float)dd2;
      float r = 1.0f / sqrtf(fd);
      n1[row] = r;
      n2[row] = r / fd;
    }
    cur[t] = excl;
  }
  __syncthreads();
  for (int i = s0 + t; i < s1; i += 256) {
    int2 p = pairs[i];
    int off = atomicAdd(&cur[p.y - lo], 1);
    colidx[s0 + off] = p.x;
  }
  if (b == 0 && t == 0) rowptr[N] = E;
}

// ---------------------------------------------------------------------------
// agg[i] = ( sum_{e in row i} h16[col[e]] ) * n2[i]   (n1 folded into h16)
// ---------------------------------------------------------------------------
__global__ __launch_bounds__(256) void agg_kernel(const __half* __restrict__ h16,
                                                  const int* __restrict__ rowptr,
                                                  const int* __restrict__ colidx,
                                                  const float* __restrict__ n2,
                                                  float* __restrict__ agg, int N) {
  int wid = (blockIdx.x * 256 + threadIdx.x) >> 6;
  int lane = threadIdx.x & 63;
  if (wid >= N) return;
  int s = rowptr[wid], e = rowptr[wid + 1];
  const __half2* h2 = (const __half2*)h16;
  float ax[4] = {0.f, 0.f, 0.f, 0.f};
  float ay[4] = {0.f, 0.f, 0.f, 0.f};
  for (int i = s; i < e; i += 8) {
    int c[8];
#pragma unroll
    for (int j = 0; j < 8; ++j) {
      int idx = i + j;
      c[j] = colidx[idx < e ? idx : e - 1];
    }
    __half2 v[8];
#pragma unroll
    for (int j = 0; j < 8; ++j) v[j] = h2[(size_t)c[j] * 64 + lane];
#pragma unroll
    for (int j = 0; j < 8; ++j) {
      float2 f = __half22float2(v[j]);
      bool ok = (i + j) < e;
      ax[j & 3] += ok ? f.x : 0.f;
      ay[j & 3] += ok ? f.y : 0.f;
    }
  }
  float m = n2[wid];
  float axs = (ax[0] + ax[1]) + (ax[2] + ax[3]);
  float ays = (ay[0] + ay[1]) + (ay[2] + ay[3]);
  ((float2*)agg)[(size_t)wid * 64 + lane] = make_float2(axs * m, ays * m);
}

// ---------------------------------------------------------------------------
// Weight prep, single launch (transposed [C][K] + hi/lo split)
// ---------------------------------------------------------------------------
__global__ __launch_bounds__(256) void prep_all(
    const float* __restrict__ encW, const float* __restrict__ W1,
    const float* __restrict__ W2, unsigned short* __restrict__ encWh,
    unsigned short* __restrict__ encWl, unsigned short* __restrict__ W1th,
    unsigned short* __restrict__ W1tl, unsigned short* __restrict__ W2th,
    unsigned short* __restrict__ W2tl, int L) {
  int t = blockIdx.x * 256 + threadIdx.x;
  const int n1e = 16384;
  const int n2e = n1e + L * 32768;
  const int n3e = n2e + L * 16384;
  unsigned int h, l;
  if (t < n1e) {
    int c = t >> 7, k = t & 127;
    split2(encW[k * 128 + c], h, l);
    encWh[t] = (unsigned short)h; encWl[t] = (unsigned short)l;
  } else if (t < n2e) {
    int u = t - n1e;
    int ll = u >> 15, w = u & 32767;
    int c = w >> 8, k = w & 255;
    split2(W1[(size_t)ll * 32768 + k * 128 + c], h, l);
    W1th[u] = (unsigned short)h; W1tl[u] = (unsigned short)l;
  } else if (t < n3e) {
    int u = t - n2e;
    int ll = u >> 14, w = u & 16383;
    int c = w >> 7, k = w & 127;
    split2(W2[(size_t)ll * 16384 + k * 128 + c], h, l);
    W2th[u] = (unsigned short)h; W2tl[u] = (unsigned short)l;
  }
}

// ---------------------------------------------------------------------------
// Fused MFMA kernel, BK=64 subtiles, 64KB LDS -> 2 blocks/CU.
// KIND 0: out = A@W1 + b1 (encoder). KIND 1: full fused layer.
// Also emits h16[row] = fp16(out[row] * n1[row]).
// LDS per subtile: As[128 rows][64 k] hi/lo + Ws[128 cols][64 k] hi/lo.
// Swizzle: 16B chunk index (k>>3) ^= (row & 7).
// ---------------------------------------------------------------------------
template <int KIND>
__global__ __launch_bounds__(512, 4) void sage_mm(
    const float* __restrict__ A, const float* __restrict__ A2,
    const unsigned short* __restrict__ W1h, const unsigned short* __restrict__ W1l,
    const unsigned short* __restrict__ W2h, const unsigned short* __restrict__ W2l,
    const float* __restrict__ b1, const float* __restrict__ b2,
    const float* __restrict__ n1, float* __restrict__ out,
    __half* __restrict__ h16, int M) {
  __shared__ unsigned short AsH[128 * 64];
  __shared__ unsigned short AsL[128 * 64];
  __shared__ unsigned short WsH[128 * 64];
  __shared__ unsigned short WsL[128 * 64];

  const int t = threadIdx.x;
  const int lane = t & 63;
  const int w = t >> 6;
  const int rl = lane & 15, g = lane >> 4;
  const int rbase = (w >> 2) * 64;
  const int cbase = (w & 3) * 32;
  const int rowbase = blockIdx.x * 128;

  // stage [128 cols][64 k] bf16 pair: 1024 chunks, 2 per thread
  auto stageW = [&](const unsigned short* sh, const unsigned short* sl, int ldk,
                    int k0) {
#pragma unroll
    for (int j = 0; j < 2; ++j) {
      int ch = t * 2 + j;
      int c = ch >> 3, cc = ch & 7;
      int off = c * 128 + ((cc ^ (c & 7)) << 4);
      *(int4*)((char*)WsH + off) = *(const int4*)(sh + (size_t)c * ldk + k0 + cc * 8);
      *(int4*)((char*)WsL + off) = *(const int4*)(sl + (size_t)c * ldk + k0 + cc * 8);
    }
  };

  // stage [128 rows][64 k] from fp32 src cols [k0,k0+64)
  auto stageA = [&](const float* __restrict__ src, int k0) {
    int r = t >> 2, kc = (t & 3) * 16;
    int grow = rowbase + r;
    const float4* s = (const float4*)(src + (size_t)grow * 128 + k0 + kc);
#pragma unroll
    for (int j = 0; j < 4; ++j) {
      float4 v = make_float4(0.f, 0.f, 0.f, 0.f);
      if (grow < M) v = s[j];
      unsigned int h0, l0, h1, l1, h2, l2, h3, l3;
      split2(v.x, h0, l0); split2(v.y, h1, l1);
      split2(v.z, h2, l2); split2(v.w, h3, l3);
      int k = kc + j * 4;
      int off = r * 128 + (((k >> 3) ^ (r & 7)) << 4) + (k & 7) * 2;
      *(int2*)((char*)AsH + off) =
          make_int2((int)(h0 | (h1 << 16)), (int)(h2 | (h3 << 16)));
      *(int2*)((char*)AsL + off) =
          make_int2((int)(l0 | (l1 << 16)), (int)(l2 | (l3 << 16)));
    }
  };

  f32x4 acc[4][2];
  auto zacc = [&]() {
#pragma unroll
    for (int i = 0; i < 4; ++i)
#pragma unroll
      for (int j = 0; j < 2; ++j) {
        f32x4 z = {0.f, 0.f, 0.f, 0.f};
        acc[i][j] = z;
      }
  };

  auto kloop = [&]() {
#pragma unroll
    for (int ks = 0; ks < 2; ++ks) {
      short8 aH[4], aL[4], bH[2], bL[2];
#pragma unroll
      for (int fr = 0; fr < 4; ++fr) {
        int row = rbase + fr * 16 + rl;
        int off = row * 128 + (((ks * 4 + g) ^ (row & 7)) << 4);
        aH[fr] = *(const short8*)((const char*)AsH + off);
        aL[fr] = *(const short8*)((const char*)AsL + off);
      }
#pragma unroll
      for (int fc = 0; fc < 2; ++fc) {
        int col = cbase + fc * 16 + rl;
        int off = col * 128 + (((ks * 4 + g) ^ (col & 7)) << 4);
        bH[fc] = *(const short8*)((const char*)WsH + off);
        bL[fc] = *(const short8*)((const char*)WsL + off);
      }
#pragma unroll
      for (int fr = 0; fr < 4; ++fr)
#pragma unroll
        for (int fc = 0; fc < 2; ++fc) {
          acc[fr][fc] = __builtin_amdgcn_mfma_f32_16x16x32_bf16(
              aH[fr], bH[fc], acc[fr][fc], 0, 0, 0);
          acc[fr][fc] = __builtin_amdgcn_mfma_f32_16x16x32_bf16(
              aH[fr], bL[fc], acc[fr][fc], 0, 0, 0);
          acc[fr][fc] = __builtin_amdgcn_mfma_f32_16x16x32_bf16(
              aL[fr], bH[fc], acc[fr][fc], 0, 0, 0);
        }
    }
  };

  // z = relu(acc + b1) staged into As cols [c0,c0+64)
  auto zstage = [&](int c0) {
#pragma unroll
    for (int fc = 0; fc < 2; ++fc) {
      int col = cbase + fc * 16 + rl;
      unsigned int lc = (unsigned int)(col - c0);
      if (lc < 64u) {
        float bb = b1[col];
#pragma unroll
        for (int fr = 0; fr < 4; ++fr)
#pragma unroll
          for (int q = 0; q < 4; ++q) {
            int row = rbase + fr * 16 + g * 4 + q;
            float z = fmaxf(acc[fr][fc][q] + bb, 0.f);
            unsigned int h, l;
            split2(z, h, l);
            int off = row * 128 + (((lc >> 3) ^ (row & 7)) << 4) + (lc & 7) * 2;
            *(unsigned short*)((char*)AsH + off) = (unsigned short)h;
            *(unsigned short*)((char*)AsL + off) = (unsigned short)l;
          }
      }
    }
  };

  zacc();
  if (KIND == 0) {
    stageA(A, 0);  stageW(W1h, W1l, 128, 0);
    __syncthreads(); kloop(); __syncthreads();
    stageA(A, 64); stageW(W1h, W1l, 128, 64);
    __syncthreads(); kloop();
#pragma unroll
    for (int fc = 0; fc < 2; ++fc) {
      int col = cbase + fc * 16 + rl;
      float bb = b1[col];
#pragma unroll
      for (int fr = 0; fr < 4; ++fr)
#pragma unroll
        for (int q = 0; q < 4; ++q) {
          int row = rowbase + rbase + fr * 16 + g * 4 + q;
          if (row < M) {
            float val = acc[fr][fc][q] + bb;
            out[(size_t)row * 128 + col] = val;
            h16[(size_t)row * 128 + col] = __float2half(val * n1[row]);
          }
        }
    }
    return;
  }

  // GEMM1: [h | agg] @ W1  (4 subtiles of K=64)
  stageA(A, 0);   stageW(W1h, W1l, 256, 0);
  __syncthreads(); kloop(); __syncthreads();
  stageA(A, 64);  stageW(W1h, W1l, 256, 64);
  __syncthreads(); kloop(); __syncthreads();
  stageA(A2, 0);  stageW(W1h, W1l, 256, 128);
  __syncthreads(); kloop(); __syncthreads();
  stageA(A2, 64); stageW(W1h, W1l, 256, 192);
  __syncthreads(); kloop(); __syncthreads();

  // GEMM2: z @ W2 (2 subtiles); z staged from acc
  zstage(0); stageW(W2h, W2l, 128, 0);
  f32x4 acc1[4][2];
#pragma unroll
  for (int i = 0; i < 4; ++i)
#pragma unroll
    for (int j = 0; j < 2; ++j) acc1[i][j] = acc[i][j];
  zacc();
  __syncthreads(); kloop(); __syncthreads();
  // restore z producer view for second half
#pragma unroll
  for (int i = 0; i < 4; ++i)
#pragma unroll
    for (int j = 0; j < 2; ++j) {
      f32x4 tmp = acc[i][j];
      acc[i][j] = acc1[i][j];
      acc1[i][j] = tmp;
    }
  zstage(64); stageW(W2h, W2l, 128, 64);
#pragma unroll
  for (int i = 0; i < 4; ++i)
#pragma unroll
    for (int j = 0; j < 2; ++j) acc[i][j] = acc1[i][j];
  __syncthreads(); kloop();

  // out = A + relu(acc + b2);  h16 = fp16(out * n1)
#pragma unroll
  for (int fc = 0; fc < 2; ++fc) {
    int col = cbase + fc * 16 + rl;
    float bb = b2[col];
#pragma unroll
    for (int fr = 0; fr < 4; ++fr)
#pragma unroll
      for (int q = 0; q < 4; ++q) {
        int row = rowbase + rbase + fr * 16 + g * 4 + q;
        if (row < M) {
          float z = fmaxf(acc[fr][fc][q] + bb, 0.f);
          float val = A[(size_t)row * 128 + col] + z;
          out[(size_t)row * 128 + col] = val;
          h16[(size_t)row * 128 + col] = __float2half(val * n1[row]);
        }
      }
  }
}

// ---------------------------------------------------------------------------
// Pooling + readout
// ---------------------------------------------------------------------------
__global__ __launch_bounds__(256) void pool_partial(const float* __restrict__ h,
                                                    float* __restrict__ partial,
                                                    int N) {
  int col = threadIdx.x & 127;
  int stream = blockIdx.x * 2 + (threadIdx.x >> 7);
  float s = 0.f;
  for (int r = stream; r < N; r += 512) s += h[(size_t)r * 128 + col];
  partial[stream * 128 + col] = s;
}

__global__ __launch_bounds__(256) void readout_kernel(
    const float* __restrict__ partial, const float* __restrict__ rW1,
    const float* __restrict__ rb1, const float* __restrict__ rW2,
    const float* __restrict__ rb2, const float* __restrict__ rW3,
    const float* __restrict__ rb3, float* __restrict__ outp, int N) {
  __shared__ float pooled[128];
  __shared__ float x1[64];
  __shared__ float x2[32];
  int t = threadIdx.x;
  if (t < 128) {
    float s = 0.f;
    for (int i = 0; i < 512; ++i) s += partial[i * 128 + t];
    pooled[t] = s / (float)N;
  }
  __syncthreads();
  if (t < 64) {
    float s = rb1[t];
    for (int k = 0; k < 128; ++k) s = fmaf(pooled[k], rW1[k * 64 + t], s);
    x1[t] = fmaxf(s, 0.f);
  }
  __syncthreads();
  if (t < 32) {
    float s = rb2[t];
    for (int k = 0; k < 64; ++k) s = fmaf(x1[k], rW2[k * 32 + t], s);
    x2[t] = fmaxf(s, 0.f);
  }
  __syncthreads();
  if (t < 10) {
    float s = rb3[t];
    for (int k = 0; k < 32; ++k) s = fmaf(x2[k], rW3[k * 10 + t], s);
    outp[t] = s;
  }
}

extern "C" void kernel_launch(void* const* d_in, const int* in_sizes, int n_in,
                              void* d_out, int out_size, void* d_ws, size_t ws_size,
                              hipStream_t stream) {
  const float* h_in  = (const float*)d_in[0];
  const int*   src   = (const int*)d_in[1];
  const int*   dst   = (const int*)d_in[2];
  const float* enc_W = (const float*)d_in[3];
  const float* enc_b = (const float*)d_in[4];
  const float* W1    = (const float*)d_in[5];
  const float* b1    = (const float*)d_in[6];
  const float* W2    = (const float*)d_in[7];
  const float* b2    = (const float*)d_in[8];
  const float* rW1   = (const float*)d_in[9];
  const float* rb1   = (const float*)d_in[10];
  const float* rW2   = (const float*)d_in[11];
  const float* rb2   = (const float*)d_in[12];
  const float* rW3   = (const float*)d_in[13];
  const float* rb3   = (const float*)d_in[14];

  const int N = in_sizes[0] / 128;
  const int E = in_sizes[1];
  const int L = in_sizes[6] / 128;
  const int NB = (N + 127) >> 7;
  const int chunk = (E + 63) / 64;

  char* ws = (char*)d_ws;
  size_t off = 0;
  auto alloc = [&](size_t bytes) {
    char* p = ws + off;
    off = (off + bytes + 511) & ~(size_t)511;
    return p;
  };
  float* h        = (float*)alloc((size_t)N * 128 * 4);
  float* agg      = (float*)alloc((size_t)N * 128 * 4);
  __half* h16     = (__half*)alloc((size_t)N * 128 * 2);
  int* rowptr     = (int*)alloc((size_t)(N + 1) * 4);
  int* colidx     = (int*)alloc((size_t)E * 4);
  float* n1       = (float*)alloc((size_t)N * 4);
  float* n2       = (float*)alloc((size_t)N * 4);
  int* histG      = (int*)alloc((size_t)NB * 64 * 4);
  int* bucketStart= (int*)alloc((size_t)(NB + 1) * 4);
  float* partial  = (float*)alloc((size_t)512 * 128 * 4);
  unsigned short* encWh = (unsigned short*)alloc(16384 * 2);
  unsigned short* encWl = (unsigned short*)alloc(16384 * 2);
  unsigned short* W1th  = (unsigned short*)alloc((size_t)L * 32768 * 2);
  unsigned short* W1tl  = (unsigned short*)alloc((size_t)L * 32768 * 2);
  unsigned short* W2th  = (unsigned short*)alloc((size_t)L * 16384 * 2);
  unsigned short* W2tl  = (unsigned short*)alloc((size_t)L * 16384 * 2);
  int2* pairs = (int2*)agg;  // alias: pairs dead after bucketC
  (void)ws_size; (void)n_in; (void)out_size;

  {
    int tot = 16384 + L * 32768 + L * 16384;
    prep_all<<<(tot + 255) / 256, 256, 0, stream>>>(
        enc_W, W1, W2, encWh, encWl, W1th, W1tl, W2th, W2tl, L);
  }

  bucketA<<<64, 256, 0, stream>>>(dst, histG, E, chunk, NB);
  bucketS<<<1, 1024, 0, stream>>>(histG, bucketStart, NB);
  bucketB<<<64, 256, 0, stream>>>(src, dst, histG, bucketStart, pairs, E, chunk, NB);
  bucketC<<<NB, 256, 0, stream>>>(pairs, bucketStart, rowptr, colidx, n1, n2, N, E);

  const int gblocks = (N + 127) / 128;
  sage_mm<0><<<gblocks, 512, 0, stream>>>(h_in, nullptr, encWh, encWl, nullptr,
                                          nullptr, enc_b, nullptr, n1, h, h16, N);
  for (int l = 0; l < L; ++l) {
    agg_kernel<<<(N + 3) / 4, 256, 0, stream>>>(h16, rowptr, colidx, n2, agg, N);
    sage_mm<1><<<gblocks, 512, 0, stream>>>(
        h, agg, W1th + (size_t)l * 32768, W1tl + (size_t)l * 32768,
        W2th + (size_t)l * 16384, W2tl + (size_t)l * 16384,
        b1 + l * 128, b2 + l * 128, n1, h, h16, N);
  }
  pool_partial<<<256, 256, 0, stream>>>(h, partial, N);
  readout_kernel<<<1, 256, 0, stream>>>(partial, rW1, rb1, rW2, rb2, rW3, rb3,
                                        (float*)d_out, N);
}